// Round 10
// baseline (698.684 us; speedup 1.0000x reference)
//
#include <hip/hip_runtime.h>
#include <hip/hip_bf16.h>
#include <stdint.h>

// ---------------------------------------------------------------------------
// B=256 D=28 N=23 F=128 O=64 H=128 Y=7.  NBSEQ=5888 = 184 blocks x 32 seqs.
// R10:
//  kernB: 1024 threads (16 waves), 2 M-tiles/wave (acc[2][2]=16 VGPR, c in
//         registers).  Doubles waves/SIMD 2->4 (latency hiding), cuts per-lane
//         live regs ~120->~90 (kills the 34MB residual spill), gives the
//         allocator room for deep weight prefetch.  LDS 117->85KB (c-slots
//         dropped).  +1 barrier fixing the step-27 mean-build/step-28 L0 race.
//  kernA/kernPrep: unchanged R9 (MFMA A2/A7; out of top-5).
// ---------------------------------------------------------------------------

#define DB 256
#define DD 28
#define DN 23
#define DF 128
#define DO 64
#define DH 128
#define DY 7
#define NBSEQ (DN*DB)
#define ADJSZ (DB*DD*DN*DN)
#define GBLK 184

// workspace byte offsets
#define WB0_OFF   47480832u            // zlin = 7168*414*16
#define WB1_OFF   47710208u
#define WPK_OFF   47972352u
#define GPK_OFF   48103424u

using v8bf  = __attribute__((ext_vector_type(8))) __bf16;
using f32x4 = __attribute__((ext_vector_type(4))) float;
using u32x4 = __attribute__((ext_vector_type(4))) unsigned int;

__device__ __forceinline__ float fsig(float x)  { return 1.f/(1.f+__expf(-x)); }
__device__ __forceinline__ float ftanh(float x) { return 1.f - 2.f/(__expf(2.f*x)+1.f); }

__device__ __forceinline__ unsigned short f2bf(float f){
    unsigned u = __builtin_bit_cast(unsigned, f);
    return (unsigned short)((u + 0x7FFFu + ((u>>16)&1u)) >> 16);
}
__device__ __forceinline__ float bf2f(unsigned short b){
    return __builtin_bit_cast(float, (unsigned)b << 16);
}
__device__ __forceinline__ uint4 ntload4(const uint4* p){
    u32x4 v = __builtin_nontemporal_load((const u32x4*)p);
    return *(uint4*)&v;
}

#define MFMA_(acc_, A_, B_) acc_ = __builtin_amdgcn_mfma_f32_16x16x32_bf16(A_, B_, acc_, 0, 0, 0)

// ---------------------------------------------------------------------------
// Prep (unchanged R9)
// ---------------------------------------------------------------------------
__global__ __launch_bounds__(256) void kernPrep(
    const float* __restrict__ wih0, const float* __restrict__ whh0,
    const float* __restrict__ wih1, const float* __restrict__ whh1,
    const float* __restrict__ glw1, const float* __restrict__ glw2,
    const float* __restrict__ gcn_w,
    unsigned short* __restrict__ wb0, unsigned short* __restrict__ wb1,
    unsigned short* __restrict__ wpk, unsigned short* __restrict__ gpk)
{
    int idx = blockIdx.x*256 + threadIdx.x;
    if (idx < 114688){
        int e = idx&7, l = (idx>>3)&63, mt = (idx>>9)&31, kt = idx>>14;
        int rit = l&15, lj = rit>>2, g = rit&3;
        int r = g*128 + (mt>>2)*16 + lj*4 + (mt&3);
        int k = kt*32 + (l>>4)*8 + e;
        float v = 0.f;
        if (k < 65)                  v = wih0[r*65 + k];
        else if (k >= 72 && k < 200) v = whh0[r*128 + (k-72)];
        wb0[idx] = f2bf(v);
        return;
    }
    idx -= 114688;
    if (idx < 131072){
        int e = idx&7, l = (idx>>3)&63, mt = (idx>>9)&31, kt = idx>>14;
        int rit = l&15, lj = rit>>2, g = rit&3;
        int r = g*128 + (mt>>2)*16 + lj*4 + (mt&3);
        int k = kt*32 + (l>>4)*8 + e;
        float v = (k < 128) ? wih1[r*128 + k] : whh1[r*128 + (k-128)];
        wb1[idx] = f2bf(v);
        return;
    }
    idx -= 131072;
    if (idx < 65536){
        int e = idx&7, l = (idx>>3)&63, hsel = (idx>>9)&1, kt = (idx>>10)&3,
            nt = (idx>>12)&7, mat = (idx>>15)&1;
        int fo = nt*16 + (l&15);
        int k  = kt*32 + (l>>4)*8 + e;
        float v = (mat ? glw2 : glw1)[fo*128 + k];
        unsigned short hb = f2bf(v);
        wpk[idx] = hsel ? f2bf(v - bf2f(hb)) : hb;
        return;
    }
    idx -= 65536;
    if (idx < 8192){
        int e = idx&7, l = (idx>>3)&63, kt = (idx>>9)&3, nt = (idx>>11)&3;
        int o = nt*16 + (l&15);
        int k = kt*32 + (l>>4)*8 + e;
        gpk[idx] = f2bf(gcn_w[k*64 + o]);
    }
}

// ---------------------------------------------------------------------------
// Kernel A (unchanged R9): per-(b,d) graph stage -> adj + zlin[bd][414].
// ---------------------------------------------------------------------------
__global__ __launch_bounds__(256) void kernA(
    const float* __restrict__ x, const float* __restrict__ adj_real,
    const float* __restrict__ infection, const int* __restrict__ day_order,
    const float* __restrict__ b1, const float* __restrict__ b2,
    const float* __restrict__ glp, const float* __restrict__ vvec,
    const v8bf* __restrict__ wpk, const v8bf* __restrict__ gpk,
    float* __restrict__ out_adj, uint4* __restrict__ zlin4)
{
    const int bd = blockIdx.x;
    const int b  = bd / DD;
    const int t  = threadIdx.x;
    const int w  = t>>6, l = t&63;

    __shared__ float sm[8740];
    const int N1=0, N2=3036, S12=6072, ADJ=6624, XW=7176, DEG=8648,
              DINV=8671, FACT=8694, INFS=8717;
    const int GC = N1;
    __shared__ __align__(16) unsigned short xhl[2][32][140];

    const float* xg = x + (size_t)bd*(DN*DF);
    for (int p=t; p<DN*DF; p+=256){
        int n = p>>7, k = p&127;
        float v = xg[p];
        unsigned short hb = f2bf(v);
        xhl[0][n][k] = hb;
        xhl[1][n][k] = f2bf(v - bf2f(hb));
    }
    for (int p=t; p<9*DF; p+=256){
        int n = DN + (p>>7), k = p&127;
        xhl[0][n][k] = 0; xhl[1][n][k] = 0;
    }
    if (t < DN){
        float vv = vvec[t];
        sm[FACT+t] = __expf(vv*vv*(float)day_order[b]);
        sm[INFS+t] = infection[(size_t)bd*DN + t];
    }
    __syncthreads();

    {
        const int mat = w>>1;
        const int ntb = (w&1)*4;
        const float* bsrc = mat ? b2 : b1;
        float bias[4];
        #pragma unroll
        for (int q=0;q<4;q++) bias[q] = bsrc[(ntb+q)*16 + (l&15)];
        f32x4 acc[2][4];
        #pragma unroll
        for (int mt=0;mt<2;mt++)
            #pragma unroll
            for (int q=0;q<4;q++){ f32x4 z; z[0]=z[1]=z[2]=z[3]=0.f; acc[mt][q]=z; }
        #pragma unroll
        for (int kt=0;kt<4;kt++){
            v8bf ah[2], al[2];
            #pragma unroll
            for (int mt=0;mt<2;mt++){
                int m = mt*16 + (l&15);
                int ko = (l>>4)*8 + kt*32;
                ah[mt] = *(const v8bf*)&xhl[0][m][ko];
                al[mt] = *(const v8bf*)&xhl[1][m][ko];
            }
            #pragma unroll
            for (int q=0;q<4;q++){
                const v8bf* wb = wpk + ((size_t)(((mat*8+(ntb+q))*4+kt)*2)*64 + l);
                v8bf wh = wb[0], wl = wb[64];
                MFMA_(acc[0][q], ah[0], wh);
                MFMA_(acc[1][q], ah[1], wh);
                MFMA_(acc[0][q], al[0], wh);
                MFMA_(acc[1][q], al[1], wh);
                MFMA_(acc[0][q], ah[0], wl);
                MFMA_(acc[1][q], ah[1], wl);
            }
        }
        const int dst = mat ? N2 : N1;
        #pragma unroll
        for (int mt=0;mt<2;mt++){
            #pragma unroll
            for (int q=0;q<4;q++){
                int fo = (ntb+q)*16 + (l&15);
                #pragma unroll
                for (int r=0;r<4;r++){
                    int n = mt*16 + (l>>4)*4 + r;
                    if (n < DN) sm[dst + n*132 + fo] = ftanh(acc[mt][q][r] + bias[q]);
                }
            }
        }
    }
    __syncthreads();

    if (t < DN){
        const float* ar = adj_real + (size_t)bd*(DN*DN) + t*DN;
        float s = 0.f;
        for (int m=0;m<DN;m++) s += ar[m];
        sm[DEG+t] = s;
    }
    for (int p=t; p<DN*DN; p+=256){
        int i = p/DN, j = p - i*DN;
        float a = 0.f;
        for (int k4=0;k4<32;k4++){
            const float4 av = *(const float4*)&sm[N1 + i*132 + 4*k4];
            const float4 bv = *(const float4*)&sm[N2 + j*132 + 4*k4];
            a = fmaf(av.w,bv.w, fmaf(av.z,bv.z, fmaf(av.y,bv.y, fmaf(av.x,bv.x,a))));
        }
        sm[S12 + i*24 + j] = a;
    }
    __syncthreads();

    for (int p=t; p<DN*DN; p+=256){
        int i=p/DN, j=p-i*DN;
        float al  = fmaxf(ftanh(sm[S12+i*24+j]-sm[S12+j*24+i]), 0.f);
        float md  = fsig(glp[i*DN+j]*sm[DEG+i]*sm[DEG+j]);
        float arv = adj_real[(size_t)bd*(DN*DN) + p];
        float adjv = al + md*arv;
        __builtin_nontemporal_store(adjv, &out_adj[(size_t)bd*(DN*DN) + p]);
        sm[ADJ + i*24 + j] = adjv + (i==j ? 1.f : 0.f);
    }
    __syncthreads();

    if (t<DN){
        float rs=0.f;
        for (int jj=0;jj<DN;jj++) rs += sm[ADJ+t*24+jj];
        sm[DINV+t] = rsqrtf(rs);
    }
    __syncthreads();

    for (int p=t;p<DN*DN;p+=256){
        int i=p/DN, j=p-i*DN;
        sm[ADJ+i*24+j] *= sm[DINV+i]*sm[DINV+j];
    }
    {
        f32x4 acc2[2];
        { f32x4 z; z[0]=z[1]=z[2]=z[3]=0.f; acc2[0]=z; acc2[1]=z; }
        #pragma unroll
        for (int kt=0;kt<4;kt++){
            v8bf ah[2], al[2];
            #pragma unroll
            for (int mt=0;mt<2;mt++){
                int m = mt*16 + (l&15);
                int ko = (l>>4)*8 + kt*32;
                ah[mt] = *(const v8bf*)&xhl[0][m][ko];
                al[mt] = *(const v8bf*)&xhl[1][m][ko];
            }
            v8bf gh = gpk[(size_t)(w*4+kt)*64 + l];
            MFMA_(acc2[0], ah[0], gh);
            MFMA_(acc2[1], ah[1], gh);
            MFMA_(acc2[0], al[0], gh);
            MFMA_(acc2[1], al[1], gh);
        }
        int o = w*16 + (l&15);
        #pragma unroll
        for (int mt=0;mt<2;mt++){
            #pragma unroll
            for (int r=0;r<4;r++){
                int n = mt*16 + (l>>4)*4 + r;
                if (n < DN) sm[XW + n*64 + o] = acc2[mt][r];
            }
        }
    }
    __syncthreads();

    for (int p=t;p<DN*64;p+=256){
        int n=p>>6, o=p&63;
        float a=0.f;
        #pragma unroll
        for (int m=0;m<DN;m++) a = fmaf(sm[ADJ+n*24+m], sm[XW+m*64+o], a);
        sm[GC + p] = fmaxf(a,0.f)*sm[FACT+n];
    }
    __syncthreads();

    for (int p=t; p<DN*18; p+=256){
        int n = p/18, r = p - n*18, hsel = r/9, k8 = r - hsel*9;
        __align__(16) unsigned short ob[8];
        #pragma unroll
        for (int e=0;e<8;e++){
            int k = k8*8+e;
            float v = (k<64) ? sm[GC + n*64 + k] : ((k==64) ? sm[INFS+n] : 0.f);
            unsigned short hb = f2bf(v);
            ob[e] = hsel ? f2bf(v - bf2f(hb)) : hb;
        }
        zlin4[(size_t)bd*414 + p] = *(const uint4*)ob;
    }
}

// ---------------------------------------------------------------------------
// Kernel B: MFMA LSTM.  grid=184, block=1024 (16 waves), 32 seqs/block.
// Wave w: M-tiles 2w, 2w+1; j(mi) = ((2w+mi)>>2)*16 + lhi*4 + ((2w+mi)&3).
// acc[2][2] (16 VGPR), c-states in registers.  Waves 0..8 stage x (t<576).
// ---------------------------------------------------------------------------
#define XB0O 0
#define XB1O 9216
#define H0O  18432          // hi 19x512 = 9728 ; lo at +9728 (19x512)
#define U1O  37888          // hi 32x512 = 16384 ; lo at +16384
#define X2O  70656          // [8][288] f32 = 9216
#define B0O  79872          // 512 f32
#define B1O  81920
#define FCO  83968          // 129 f32
#define INO  84488          // 32 f32
// end 84616

__global__ __launch_bounds__(1024, 4) void kernB(
    const uint4* __restrict__ zlin, const v8bf* __restrict__ w0p, const v8bf* __restrict__ w1p,
    const float* __restrict__ b0g, const float* __restrict__ b1g,
    const float* __restrict__ infection, const float* __restrict__ fcw,
    const float* __restrict__ fcb, float* __restrict__ outy)
{
    const int t = threadIdx.x, blk = blockIdx.x;
    const int w = t>>6, l = t&63;
    const int lhi = l>>4, llo = l&15;
    __shared__ __align__(16) unsigned char smraw[84616];
    char* smb = (char*)smraw;

    // zero H0..X2 end (18432..79872)
    {
        uint4 z; z.x=z.y=z.z=z.w=0u;
        for (int i = t; i < (79872-18432)/16; i += 1024) ((uint4*)(smb+18432))[i] = z;
    }
    if (t < 512){
        ((float*)(smb+B0O))[t] = b0g[t];
        ((float*)(smb+B1O))[t] = b1g[t];
    }
    if (t < 129) ((float*)(smb+FCO))[t] = (t<128) ? fcw[t] : fcb[0];
    if (t < 32){
        int gseq = blk*32 + t, n = gseq>>8, bb = gseq&255;
        float a = 0.f;
        for (int dd=0; dd<DD; dd++)
            a = fmaf(fcw[128+dd], infection[((size_t)bb*DD+dd)*DN+n], a);
        ((float*)(smb+INO))[t] = a;
    }

    // staging constants (waves 0..8: t<576, unit u = t)
    int hs1 = (t >= 288) ? 1 : 0;  int rm1 = t - hs1*288;
    int k81 = rm1 >> 5, sq1 = rm1 & 31;
    int gs1 = blk*32 + sq1;
    size_t cb1 = (size_t)(gs1 & 255)*DD*414 + (gs1>>8)*18 + hs1*9 + k81;
    int d1 = t*16;

    // output-tile constants
    const int mt0 = 2*w;
    const int jt  = mt0>>2, r3 = mt0&3;
    const int j8  = jt*2 + (lhi>>1);
    const int sub = (lhi&1)*8 + r3*2;
    const int j0  = jt*16 + lhi*4 + r3;

    float c0[2][2] = {}, c1[2][2] = {};
    __syncthreads();

    // prologue: stage x(0) into XB0
    if (t < 576){
        uint4 a0 = ntload4(zlin + cb1);
        *(uint4*)(smb + XB0O + d1) = a0;
    }
    __syncthreads();

    const float* bias0L = (const float*)(smb+B0O);
    const float* bias1L = (const float*)(smb+B1O);

    for (int step = 0; step < DD + DY; ++step){
        const int xb  = (step & 1) ? XB1O : XB0O;
        const int xbn = (step & 1) ? XB0O : XB1O;
        const bool do_stage = (step + 1 < DD);

        // ---------------- L0 MFMA (+ stage x(step+1)) ----------------
        {
            uint4 sv0; sv0.x=sv0.y=sv0.z=sv0.w=0u;
            if (do_stage && t < 576)
                sv0 = ntload4(zlin + (size_t)(step+1)*414 + cb1);

            f32x4 acc[2][2];
            #pragma unroll
            for (int mi=0;mi<2;mi++){
                int j = j0 + mi;
                f32x4 a;
                a[0]=bias0L[j]; a[1]=bias0L[128+j]; a[2]=bias0L[256+j]; a[3]=bias0L[384+j];
                acc[mi][0] = a; acc[mi][1] = a;
            }
            #pragma unroll
            for (int kt=0; kt<7; ++kt){
                const v8bf* wrow = w0p + (size_t)(kt*32 + mt0)*64 + l;
                v8bf A0 = wrow[0], A1 = wrow[64];
                int k8 = kt*4 + lhi;
                bool inx = (k8 <= 8);
                const char* hib = inx ? (smb + xb + k8*512) : (smb + H0O + (k8-9)*512);
                int losh = inx ? 4608 : 9728;
                v8bf BH0 = *(const v8bf*)(hib + llo*16);
                v8bf BH1 = *(const v8bf*)(hib + 256 + llo*16);
                v8bf BL0 = *(const v8bf*)(hib + losh + llo*16);
                v8bf BL1 = *(const v8bf*)(hib + losh + 256 + llo*16);
                MFMA_(acc[0][0], A0, BH0); MFMA_(acc[0][0], A0, BL0);
                MFMA_(acc[1][0], A1, BH0); MFMA_(acc[1][0], A1, BL0);
                MFMA_(acc[0][1], A0, BH1); MFMA_(acc[0][1], A0, BL1);
                MFMA_(acc[1][1], A1, BH1); MFMA_(acc[1][1], A1, BL1);
            }
            if (do_stage && t < 576)
                *(uint4*)(smb + xbn + d1) = sv0;
            __syncthreads();   // B1: xb/H0 reads done

            // x2 accumulation of x(step)
            if (step < DD && t < 288){
                const unsigned short* hp = (const unsigned short*)(smb + xb + t*16);
                const unsigned short* lp = (const unsigned short*)(smb + xb + 4608 + t*16);
                float* xs = (float*)(smb + X2O);
                #pragma unroll
                for (int e=0;e<8;e++) xs[e*288+t] += bf2f(hp[e]) + bf2f(lp[e]);
            }

            // ACT L0 -> h0(step)
            #pragma unroll
            for (int nt=0;nt<2;nt++){
                unsigned short hh[2], hl[2];
                #pragma unroll
                for (int mi=0;mi<2;mi++){
                    f32x4 a = acc[mi][nt];
                    float ii = fsig(a[0]), ff = fsig(a[1]), gg = ftanh(a[2]), oo = fsig(a[3]);
                    float c = ff*c0[mi][nt] + ii*gg;
                    c0[mi][nt] = c;
                    float h = oo*ftanh(c);
                    hh[mi] = f2bf(h);
                    hl[mi] = f2bf(h - bf2f(hh[mi]));
                }
                unsigned ph = (unsigned)hh[0] | ((unsigned)hh[1]<<16);
                unsigned pl = (unsigned)hl[0] | ((unsigned)hl[1]<<16);
                int bo = j8*512 + (nt*16+llo)*16 + sub;
                *(unsigned*)(smb + H0O + bo)         = ph;
                *(unsigned*)(smb + H0O + 9728 + bo)  = pl;
                *(unsigned*)(smb + U1O + bo)         = ph;
                *(unsigned*)(smb + U1O + 16384 + bo) = pl;
            }
            __syncthreads();   // B2: h0 visible
        }

        // ---------------- L1 MFMA ----------------
        {
            f32x4 acc1[2][2];
            #pragma unroll
            for (int mi=0;mi<2;mi++){
                int j = j0 + mi;
                f32x4 a;
                a[0]=bias1L[j]; a[1]=bias1L[128+j]; a[2]=bias1L[256+j]; a[3]=bias1L[384+j];
                acc1[mi][0] = a; acc1[mi][1] = a;
            }
            #pragma unroll
            for (int kt=0; kt<8; ++kt){
                const v8bf* wrow = w1p + (size_t)(kt*32 + mt0)*64 + l;
                v8bf A0 = wrow[0], A1 = wrow[64];
                const char* hib = smb + U1O + (kt*4+lhi)*512;
                v8bf BH0 = *(const v8bf*)(hib + llo*16);
                v8bf BH1 = *(const v8bf*)(hib + 256 + llo*16);
                v8bf BL0 = *(const v8bf*)(hib + 16384 + llo*16);
                v8bf BL1 = *(const v8bf*)(hib + 16384 + 256 + llo*16);
                MFMA_(acc1[0][0], A0, BH0); MFMA_(acc1[0][0], A0, BL0);
                MFMA_(acc1[1][0], A1, BH0); MFMA_(acc1[1][0], A1, BL0);
                MFMA_(acc1[0][1], A0, BH1); MFMA_(acc1[0][1], A0, BL1);
                MFMA_(acc1[1][1], A1, BH1); MFMA_(acc1[1][1], A1, BL1);
            }
            __syncthreads();   // B3: U1 reads done

            // ACT L1 -> h1(step)
            #pragma unroll
            for (int nt=0;nt<2;nt++){
                unsigned short hh[2], hl[2];
                #pragma unroll
                for (int mi=0;mi<2;mi++){
                    f32x4 a = acc1[mi][nt];
                    float ii = fsig(a[0]), ff = fsig(a[1]), gg = ftanh(a[2]), oo = fsig(a[3]);
                    float c = ff*c1[mi][nt] + ii*gg;
                    c1[mi][nt] = c;
                    float h = oo*ftanh(c);
                    hh[mi] = f2bf(h);
                    hl[mi] = f2bf(h - bf2f(hh[mi]));
                }
                unsigned ph = (unsigned)hh[0] | ((unsigned)hh[1]<<16);
                unsigned pl = (unsigned)hl[0] | ((unsigned)hl[1]<<16);
                int bo = (16+j8)*512 + (nt*16+llo)*16 + sub;
                *(unsigned*)(smb + U1O + bo)         = ph;
                *(unsigned*)(smb + U1O + 16384 + bo) = pl;
            }
        }

        // ---- step 27: build decoder mean input into BOTH XB buffers
        if (step == DD-1){
            __syncthreads();
            if (t < 288){
                const float* xs = (const float*)(smb + X2O);
                __align__(16) unsigned short hb8[8], lb8[8];
                #pragma unroll
                for (int e=0;e<8;e++){
                    float v = xs[e*288+t] * (1.f/(float)DD);
                    unsigned short h = f2bf(v);
                    hb8[e] = h;
                    lb8[e] = f2bf(v - bf2f(h));
                }
                *(uint4*)(smb + XB0O + t*16)        = *(const uint4*)hb8;
                *(uint4*)(smb + XB0O + 4608 + t*16) = *(const uint4*)lb8;
                *(uint4*)(smb + XB1O + t*16)        = *(const uint4*)hb8;
                *(uint4*)(smb + XB1O + 4608 + t*16) = *(const uint4*)lb8;
            }
            __syncthreads();   // R10 race fix: mean visible before step-28 L0 reads
        }

        // ---- decoder FC
        if (step >= DD){
            __syncthreads();   // h1 visible
            if (t < 256){
                int seq = t>>3, l8 = t&7;
                const unsigned short* uh = (const unsigned short*)(smb+U1O);
                const unsigned short* ul = (const unsigned short*)(smb+U1O+16384);
                const float* fw = (const float*)(smb+FCO);
                float a = 0.f;
                #pragma unroll
                for (int half=0; half<2; ++half){
                    int k8 = 16 + l8*2 + half;
                    int base = (k8*32 + seq)*8;
                    #pragma unroll
                    for (int e=0;e<8;e++){
                        int j = l8*16 + half*8 + e;
                        a = fmaf(fw[j], bf2f(uh[base+e]) + bf2f(ul[base+e]), a);
                    }
                }
                a += __shfl_down(a, 4, 8);
                a += __shfl_down(a, 2, 8);
                a += __shfl_down(a, 1, 8);
                if (l8 == 0){
                    int gseq = blk*32 + seq, n = gseq>>8, bb = gseq&255;
                    float yv = fmaxf(a + ((const float*)(smb+INO))[seq] + fw[128], 0.f);
                    __builtin_nontemporal_store(yv, &outy[((size_t)bb*DY + (step-DD))*DN + n]);
                }
            }
        }
        // no closing barrier for encoder steps (R7-proven scheme)
    }
}

// ---------------------------------------------------------------------------
extern "C" void kernel_launch(void* const* d_in, const int* in_sizes, int n_in,
                              void* d_out, int out_size, void* d_ws, size_t ws_size,
                              hipStream_t stream)
{
    const float* x         = (const float*)d_in[0];
    const float* adj_real  = (const float*)d_in[1];
    const float* infection = (const float*)d_in[2];
    const int*   day_order = (const int*)  d_in[3];
    const float* gl_w1     = (const float*)d_in[4];
    const float* gl_b1     = (const float*)d_in[5];
    const float* gl_w2     = (const float*)d_in[6];
    const float* gl_b2     = (const float*)d_in[7];
    const float* glp       = (const float*)d_in[8];
    const float* gcn_w     = (const float*)d_in[9];
    const float* vvec      = (const float*)d_in[10];
    const float* wih0      = (const float*)d_in[11];
    const float* whh0      = (const float*)d_in[12];
    const float* b0        = (const float*)d_in[13];
    const float* wih1      = (const float*)d_in[14];
    const float* whh1      = (const float*)d_in[15];
    const float* b1        = (const float*)d_in[16];
    const float* fcw       = (const float*)d_in[17];
    const float* fcb       = (const float*)d_in[18];

    uint8_t* wsb = (uint8_t*)d_ws;
    uint4*          zlin = (uint4*)(wsb);
    unsigned short* wb0  = (unsigned short*)(wsb + WB0_OFF);
    unsigned short* wb1  = (unsigned short*)(wsb + WB1_OFF);
    unsigned short* wpk  = (unsigned short*)(wsb + WPK_OFF);
    unsigned short* gpk  = (unsigned short*)(wsb + GPK_OFF);
    float* out_adj = (float*)d_out;
    float* out_y   = out_adj + ADJSZ;

    kernPrep<<<dim3(1248), dim3(256), 0, stream>>>(wih0, whh0, wih1, whh1,
                                                   gl_w1, gl_w2, gcn_w,
                                                   wb0, wb1, wpk, gpk);
    kernA<<<dim3(DB*DD), dim3(256), 0, stream>>>(x, adj_real, infection, day_order,
                                                 gl_b1, gl_b2, glp, vvec,
                                                 (const v8bf*)wpk, (const v8bf*)gpk,
                                                 out_adj, zlin);
    kernB<<<dim3(GBLK), dim3(1024), 0, stream>>>(zlin, (const v8bf*)wb0,
                                                 (const v8bf*)wb1, b0, b1, infection,
                                                 fcw, fcb, out_y);
}

// Round 11
// 643.564 us; speedup vs baseline: 1.0856x; 1.0856x over previous
//
#include <hip/hip_runtime.h>
#include <hip/hip_bf16.h>
#include <stdint.h>

// ---------------------------------------------------------------------------
// B=256 D=28 N=23 F=128 O=64 H=128 Y=7.  NBSEQ=5888 = 184 blocks x 32 seqs.
// R11: kernB keeps R10's 16-wave/4-per-SIMD occupancy win but fits the ~64
//      VGPR budget the allocator actually grants 1024-thread blocks:
//      c-states -> LDS slots (longest-lived regs gone), B-fragments split
//      into two half-rounds per kt (halves frag liveness), launch_bounds
//      (1024,2).  LDS 117KB (c slots added), still 1 block/CU.
//      kernA/kernPrep unchanged (R9 MFMA versions).
// ---------------------------------------------------------------------------

#define DB 256
#define DD 28
#define DN 23
#define DF 128
#define DO 64
#define DH 128
#define DY 7
#define NBSEQ (DN*DB)
#define ADJSZ (DB*DD*DN*DN)
#define GBLK 184

// workspace byte offsets
#define WB0_OFF   47480832u            // zlin = 7168*414*16
#define WB1_OFF   47710208u
#define WPK_OFF   47972352u
#define GPK_OFF   48103424u

using v8bf  = __attribute__((ext_vector_type(8))) __bf16;
using f32x4 = __attribute__((ext_vector_type(4))) float;
using u32x4 = __attribute__((ext_vector_type(4))) unsigned int;

__device__ __forceinline__ float fsig(float x)  { return 1.f/(1.f+__expf(-x)); }
__device__ __forceinline__ float ftanh(float x) { return 1.f - 2.f/(__expf(2.f*x)+1.f); }

__device__ __forceinline__ unsigned short f2bf(float f){
    unsigned u = __builtin_bit_cast(unsigned, f);
    return (unsigned short)((u + 0x7FFFu + ((u>>16)&1u)) >> 16);
}
__device__ __forceinline__ float bf2f(unsigned short b){
    return __builtin_bit_cast(float, (unsigned)b << 16);
}
__device__ __forceinline__ uint4 ntload4(const uint4* p){
    u32x4 v = __builtin_nontemporal_load((const u32x4*)p);
    return *(uint4*)&v;
}

#define MFMA_(acc_, A_, B_) acc_ = __builtin_amdgcn_mfma_f32_16x16x32_bf16(A_, B_, acc_, 0, 0, 0)

// ---------------------------------------------------------------------------
// Prep (unchanged R9)
// ---------------------------------------------------------------------------
__global__ __launch_bounds__(256) void kernPrep(
    const float* __restrict__ wih0, const float* __restrict__ whh0,
    const float* __restrict__ wih1, const float* __restrict__ whh1,
    const float* __restrict__ glw1, const float* __restrict__ glw2,
    const float* __restrict__ gcn_w,
    unsigned short* __restrict__ wb0, unsigned short* __restrict__ wb1,
    unsigned short* __restrict__ wpk, unsigned short* __restrict__ gpk)
{
    int idx = blockIdx.x*256 + threadIdx.x;
    if (idx < 114688){
        int e = idx&7, l = (idx>>3)&63, mt = (idx>>9)&31, kt = idx>>14;
        int rit = l&15, lj = rit>>2, g = rit&3;
        int r = g*128 + (mt>>2)*16 + lj*4 + (mt&3);
        int k = kt*32 + (l>>4)*8 + e;
        float v = 0.f;
        if (k < 65)                  v = wih0[r*65 + k];
        else if (k >= 72 && k < 200) v = whh0[r*128 + (k-72)];
        wb0[idx] = f2bf(v);
        return;
    }
    idx -= 114688;
    if (idx < 131072){
        int e = idx&7, l = (idx>>3)&63, mt = (idx>>9)&31, kt = idx>>14;
        int rit = l&15, lj = rit>>2, g = rit&3;
        int r = g*128 + (mt>>2)*16 + lj*4 + (mt&3);
        int k = kt*32 + (l>>4)*8 + e;
        float v = (k < 128) ? wih1[r*128 + k] : whh1[r*128 + (k-128)];
        wb1[idx] = f2bf(v);
        return;
    }
    idx -= 131072;
    if (idx < 65536){
        int e = idx&7, l = (idx>>3)&63, hsel = (idx>>9)&1, kt = (idx>>10)&3,
            nt = (idx>>12)&7, mat = (idx>>15)&1;
        int fo = nt*16 + (l&15);
        int k  = kt*32 + (l>>4)*8 + e;
        float v = (mat ? glw2 : glw1)[fo*128 + k];
        unsigned short hb = f2bf(v);
        wpk[idx] = hsel ? f2bf(v - bf2f(hb)) : hb;
        return;
    }
    idx -= 65536;
    if (idx < 8192){
        int e = idx&7, l = (idx>>3)&63, kt = (idx>>9)&3, nt = (idx>>11)&3;
        int o = nt*16 + (l&15);
        int k = kt*32 + (l>>4)*8 + e;
        gpk[idx] = f2bf(gcn_w[k*64 + o]);
    }
}

// ---------------------------------------------------------------------------
// Kernel A (unchanged R9): per-(b,d) graph stage -> adj + zlin[bd][414].
// ---------------------------------------------------------------------------
__global__ __launch_bounds__(256) void kernA(
    const float* __restrict__ x, const float* __restrict__ adj_real,
    const float* __restrict__ infection, const int* __restrict__ day_order,
    const float* __restrict__ b1, const float* __restrict__ b2,
    const float* __restrict__ glp, const float* __restrict__ vvec,
    const v8bf* __restrict__ wpk, const v8bf* __restrict__ gpk,
    float* __restrict__ out_adj, uint4* __restrict__ zlin4)
{
    const int bd = blockIdx.x;
    const int b  = bd / DD;
    const int t  = threadIdx.x;
    const int w  = t>>6, l = t&63;

    __shared__ float sm[8740];
    const int N1=0, N2=3036, S12=6072, ADJ=6624, XW=7176, DEG=8648,
              DINV=8671, FACT=8694, INFS=8717;
    const int GC = N1;
    __shared__ __align__(16) unsigned short xhl[2][32][140];

    const float* xg = x + (size_t)bd*(DN*DF);
    for (int p=t; p<DN*DF; p+=256){
        int n = p>>7, k = p&127;
        float v = xg[p];
        unsigned short hb = f2bf(v);
        xhl[0][n][k] = hb;
        xhl[1][n][k] = f2bf(v - bf2f(hb));
    }
    for (int p=t; p<9*DF; p+=256){
        int n = DN + (p>>7), k = p&127;
        xhl[0][n][k] = 0; xhl[1][n][k] = 0;
    }
    if (t < DN){
        float vv = vvec[t];
        sm[FACT+t] = __expf(vv*vv*(float)day_order[b]);
        sm[INFS+t] = infection[(size_t)bd*DN + t];
    }
    __syncthreads();

    {
        const int mat = w>>1;
        const int ntb = (w&1)*4;
        const float* bsrc = mat ? b2 : b1;
        float bias[4];
        #pragma unroll
        for (int q=0;q<4;q++) bias[q] = bsrc[(ntb+q)*16 + (l&15)];
        f32x4 acc[2][4];
        #pragma unroll
        for (int mt=0;mt<2;mt++)
            #pragma unroll
            for (int q=0;q<4;q++){ f32x4 z; z[0]=z[1]=z[2]=z[3]=0.f; acc[mt][q]=z; }
        #pragma unroll
        for (int kt=0;kt<4;kt++){
            v8bf ah[2], al[2];
            #pragma unroll
            for (int mt=0;mt<2;mt++){
                int m = mt*16 + (l&15);
                int ko = (l>>4)*8 + kt*32;
                ah[mt] = *(const v8bf*)&xhl[0][m][ko];
                al[mt] = *(const v8bf*)&xhl[1][m][ko];
            }
            #pragma unroll
            for (int q=0;q<4;q++){
                const v8bf* wb = wpk + ((size_t)(((mat*8+(ntb+q))*4+kt)*2)*64 + l);
                v8bf wh = wb[0], wl = wb[64];
                MFMA_(acc[0][q], ah[0], wh);
                MFMA_(acc[1][q], ah[1], wh);
                MFMA_(acc[0][q], al[0], wh);
                MFMA_(acc[1][q], al[1], wh);
                MFMA_(acc[0][q], ah[0], wl);
                MFMA_(acc[1][q], ah[1], wl);
            }
        }
        const int dst = mat ? N2 : N1;
        #pragma unroll
        for (int mt=0;mt<2;mt++){
            #pragma unroll
            for (int q=0;q<4;q++){
                int fo = (ntb+q)*16 + (l&15);
                #pragma unroll
                for (int r=0;r<4;r++){
                    int n = mt*16 + (l>>4)*4 + r;
                    if (n < DN) sm[dst + n*132 + fo] = ftanh(acc[mt][q][r] + bias[q]);
                }
            }
        }
    }
    __syncthreads();

    if (t < DN){
        const float* ar = adj_real + (size_t)bd*(DN*DN) + t*DN;
        float s = 0.f;
        for (int m=0;m<DN;m++) s += ar[m];
        sm[DEG+t] = s;
    }
    for (int p=t; p<DN*DN; p+=256){
        int i = p/DN, j = p - i*DN;
        float a = 0.f;
        for (int k4=0;k4<32;k4++){
            const float4 av = *(const float4*)&sm[N1 + i*132 + 4*k4];
            const float4 bv = *(const float4*)&sm[N2 + j*132 + 4*k4];
            a = fmaf(av.w,bv.w, fmaf(av.z,bv.z, fmaf(av.y,bv.y, fmaf(av.x,bv.x,a))));
        }
        sm[S12 + i*24 + j] = a;
    }
    __syncthreads();

    for (int p=t; p<DN*DN; p+=256){
        int i=p/DN, j=p-i*DN;
        float al  = fmaxf(ftanh(sm[S12+i*24+j]-sm[S12+j*24+i]), 0.f);
        float md  = fsig(glp[i*DN+j]*sm[DEG+i]*sm[DEG+j]);
        float arv = adj_real[(size_t)bd*(DN*DN) + p];
        float adjv = al + md*arv;
        __builtin_nontemporal_store(adjv, &out_adj[(size_t)bd*(DN*DN) + p]);
        sm[ADJ + i*24 + j] = adjv + (i==j ? 1.f : 0.f);
    }
    __syncthreads();

    if (t<DN){
        float rs=0.f;
        for (int jj=0;jj<DN;jj++) rs += sm[ADJ+t*24+jj];
        sm[DINV+t] = rsqrtf(rs);
    }
    __syncthreads();

    for (int p=t;p<DN*DN;p+=256){
        int i=p/DN, j=p-i*DN;
        sm[ADJ+i*24+j] *= sm[DINV+i]*sm[DINV+j];
    }
    {
        f32x4 acc2[2];
        { f32x4 z; z[0]=z[1]=z[2]=z[3]=0.f; acc2[0]=z; acc2[1]=z; }
        #pragma unroll
        for (int kt=0;kt<4;kt++){
            v8bf ah[2], al[2];
            #pragma unroll
            for (int mt=0;mt<2;mt++){
                int m = mt*16 + (l&15);
                int ko = (l>>4)*8 + kt*32;
                ah[mt] = *(const v8bf*)&xhl[0][m][ko];
                al[mt] = *(const v8bf*)&xhl[1][m][ko];
            }
            v8bf gh = gpk[(size_t)(w*4+kt)*64 + l];
            MFMA_(acc2[0], ah[0], gh);
            MFMA_(acc2[1], ah[1], gh);
            MFMA_(acc2[0], al[0], gh);
            MFMA_(acc2[1], al[1], gh);
        }
        int o = w*16 + (l&15);
        #pragma unroll
        for (int mt=0;mt<2;mt++){
            #pragma unroll
            for (int r=0;r<4;r++){
                int n = mt*16 + (l>>4)*4 + r;
                if (n < DN) sm[XW + n*64 + o] = acc2[mt][r];
            }
        }
    }
    __syncthreads();

    for (int p=t;p<DN*64;p+=256){
        int n=p>>6, o=p&63;
        float a=0.f;
        #pragma unroll
        for (int m=0;m<DN;m++) a = fmaf(sm[ADJ+n*24+m], sm[XW+m*64+o], a);
        sm[GC + p] = fmaxf(a,0.f)*sm[FACT+n];
    }
    __syncthreads();

    for (int p=t; p<DN*18; p+=256){
        int n = p/18, r = p - n*18, hsel = r/9, k8 = r - hsel*9;
        __align__(16) unsigned short ob[8];
        #pragma unroll
        for (int e=0;e<8;e++){
            int k = k8*8+e;
            float v = (k<64) ? sm[GC + n*64 + k] : ((k==64) ? sm[INFS+n] : 0.f);
            unsigned short hb = f2bf(v);
            ob[e] = hsel ? f2bf(v - bf2f(hb)) : hb;
        }
        zlin4[(size_t)bd*414 + p] = *(const uint4*)ob;
    }
}

// ---------------------------------------------------------------------------
// Kernel B: MFMA LSTM.  grid=184, block=1024 (16 waves), 32 seqs/block.
// Wave w: M-tiles 2w, 2w+1.  acc[2][2]=16 VGPR; c-states in LDS slots;
// B-fragments consumed in two half-rounds per kt (halved liveness) to fit
// the ~64-VGPR budget the allocator grants 1024-thread blocks.
// ---------------------------------------------------------------------------
#define XB0O 0
#define XB1O 9216
#define H0O  18432          // hi 19x512 = 9728 ; lo at +9728
#define U1O  37888          // hi 32x512 = 16384 ; lo at +16384
#define X2O  70656          // [8][288] f32 = 9216
#define B0O  79872          // 512 f32
#define B1O  81920
#define FCO  83968          // 129 f32
#define INO  84488          // 32 f32
#define C0O  84624          // 4 slots x 1024 f32 = 16384
#define C1O  101008         // 16384
// end 117392

__global__ __launch_bounds__(1024, 2) void kernB(
    const uint4* __restrict__ zlin, const v8bf* __restrict__ w0p, const v8bf* __restrict__ w1p,
    const float* __restrict__ b0g, const float* __restrict__ b1g,
    const float* __restrict__ infection, const float* __restrict__ fcw,
    const float* __restrict__ fcb, float* __restrict__ outy)
{
    const int t = threadIdx.x, blk = blockIdx.x;
    const int w = t>>6, l = t&63;
    const int lhi = l>>4, llo = l&15;
    __shared__ __align__(16) unsigned char smraw[117392];
    char* smb = (char*)smraw;

    // zero H0..X2 end (18432..79872) and c-slots (84624..117392)
    {
        uint4 z; z.x=z.y=z.z=z.w=0u;
        for (int i = t; i < (79872-18432)/16; i += 1024) ((uint4*)(smb+18432))[i] = z;
        for (int i = t; i < (117392-84624)/16; i += 1024) ((uint4*)(smb+84624))[i] = z;
    }
    if (t < 512){
        ((float*)(smb+B0O))[t] = b0g[t];
        ((float*)(smb+B1O))[t] = b1g[t];
    }
    if (t < 129) ((float*)(smb+FCO))[t] = (t<128) ? fcw[t] : fcb[0];
    if (t < 32){
        int gseq = blk*32 + t, n = gseq>>8, bb = gseq&255;
        float a = 0.f;
        for (int dd=0; dd<DD; dd++)
            a = fmaf(fcw[128+dd], infection[((size_t)bb*DD+dd)*DN+n], a);
        ((float*)(smb+INO))[t] = a;
    }

    // staging constants (t<576: unit u = t)
    int hs1 = (t >= 288) ? 1 : 0;  int rm1 = t - hs1*288;
    int k81 = rm1 >> 5, sq1 = rm1 & 31;
    int gs1 = blk*32 + sq1;
    size_t cb1 = (size_t)(gs1 & 255)*DD*414 + (gs1>>8)*18 + hs1*9 + k81;
    int d1 = t*16;

    // output-tile constants
    const int mt0 = 2*w;
    const int jt  = mt0>>2, r3 = mt0&3;
    const int j8  = jt*2 + (lhi>>1);
    const int sub = (lhi&1)*8 + r3*2;
    const int j0  = jt*16 + lhi*4 + r3;

    __syncthreads();

    // prologue: stage x(0) into XB0
    if (t < 576){
        uint4 a0 = ntload4(zlin + cb1);
        *(uint4*)(smb + XB0O + d1) = a0;
    }
    __syncthreads();

    const float* bias0L = (const float*)(smb+B0O);
    const float* bias1L = (const float*)(smb+B1O);

    for (int step = 0; step < DD + DY; ++step){
        const int xb  = (step & 1) ? XB1O : XB0O;
        const int xbn = (step & 1) ? XB0O : XB1O;
        const bool do_stage = (step + 1 < DD);

        // ---------------- L0 MFMA (+ stage x(step+1)) ----------------
        {
            uint4 sv0; sv0.x=sv0.y=sv0.z=sv0.w=0u;
            if (do_stage && t < 576)
                sv0 = ntload4(zlin + (size_t)(step+1)*414 + cb1);

            f32x4 acc[2][2];
            #pragma unroll
            for (int mi=0;mi<2;mi++){
                int j = j0 + mi;
                f32x4 a;
                a[0]=bias0L[j]; a[1]=bias0L[128+j]; a[2]=bias0L[256+j]; a[3]=bias0L[384+j];
                acc[mi][0] = a; acc[mi][1] = a;
            }
            #pragma unroll
            for (int kt=0; kt<7; ++kt){
                const v8bf* wrow = w0p + (size_t)(kt*32 + mt0)*64 + l;
                v8bf A0 = wrow[0], A1 = wrow[64];
                int k8 = kt*4 + lhi;
                bool inx = (k8 <= 8);
                const char* hib = inx ? (smb + xb + k8*512) : (smb + H0O + (k8-9)*512);
                int losh = inx ? 4608 : 9728;
                {   // half-round 0: nt=0 fragments only
                    v8bf BH0 = *(const v8bf*)(hib + llo*16);
                    v8bf BL0 = *(const v8bf*)(hib + losh + llo*16);
                    MFMA_(acc[0][0], A0, BH0); MFMA_(acc[0][0], A0, BL0);
                    MFMA_(acc[1][0], A1, BH0); MFMA_(acc[1][0], A1, BL0);
                }
                {   // half-round 1: nt=1 fragments
                    v8bf BH1 = *(const v8bf*)(hib + 256 + llo*16);
                    v8bf BL1 = *(const v8bf*)(hib + losh + 256 + llo*16);
                    MFMA_(acc[0][1], A0, BH1); MFMA_(acc[0][1], A0, BL1);
                    MFMA_(acc[1][1], A1, BH1); MFMA_(acc[1][1], A1, BL1);
                }
            }
            if (do_stage && t < 576)
                *(uint4*)(smb + xbn + d1) = sv0;
            __syncthreads();   // B1: xb/H0 reads done

            // x2 accumulation of x(step)
            if (step < DD && t < 288){
                const unsigned short* hp = (const unsigned short*)(smb + xb + t*16);
                const unsigned short* lp = (const unsigned short*)(smb + xb + 4608 + t*16);
                float* xs = (float*)(smb + X2O);
                #pragma unroll
                for (int e=0;e<8;e++) xs[e*288+t] += bf2f(hp[e]) + bf2f(lp[e]);
            }

            // ACT L0 -> h0(step); c in LDS slots
            #pragma unroll
            for (int nt=0;nt<2;nt++){
                unsigned short hh[2], hl[2];
                #pragma unroll
                for (int mi=0;mi<2;mi++){
                    float* cslot = (float*)(smb + C0O) + (mi*2+nt)*1024 + t;
                    f32x4 a = acc[mi][nt];
                    float ii = fsig(a[0]), ff = fsig(a[1]), gg = ftanh(a[2]), oo = fsig(a[3]);
                    float c = ff*cslot[0] + ii*gg;
                    cslot[0] = c;
                    float h = oo*ftanh(c);
                    hh[mi] = f2bf(h);
                    hl[mi] = f2bf(h - bf2f(hh[mi]));
                }
                unsigned ph = (unsigned)hh[0] | ((unsigned)hh[1]<<16);
                unsigned pl = (unsigned)hl[0] | ((unsigned)hl[1]<<16);
                int bo = j8*512 + (nt*16+llo)*16 + sub;
                *(unsigned*)(smb + H0O + bo)         = ph;
                *(unsigned*)(smb + H0O + 9728 + bo)  = pl;
                *(unsigned*)(smb + U1O + bo)         = ph;
                *(unsigned*)(smb + U1O + 16384 + bo) = pl;
            }
            __syncthreads();   // B2: h0 visible
        }

        // ---------------- L1 MFMA ----------------
        {
            f32x4 acc1[2][2];
            #pragma unroll
            for (int mi=0;mi<2;mi++){
                int j = j0 + mi;
                f32x4 a;
                a[0]=bias1L[j]; a[1]=bias1L[128+j]; a[2]=bias1L[256+j]; a[3]=bias1L[384+j];
                acc1[mi][0] = a; acc1[mi][1] = a;
            }
            #pragma unroll
            for (int kt=0; kt<8; ++kt){
                const v8bf* wrow = w1p + (size_t)(kt*32 + mt0)*64 + l;
                v8bf A0 = wrow[0], A1 = wrow[64];
                const char* hib = smb + U1O + (kt*4+lhi)*512;
                {
                    v8bf BH0 = *(const v8bf*)(hib + llo*16);
                    v8bf BL0 = *(const v8bf*)(hib + 16384 + llo*16);
                    MFMA_(acc1[0][0], A0, BH0); MFMA_(acc1[0][0], A0, BL0);
                    MFMA_(acc1[1][0], A1, BH0); MFMA_(acc1[1][0], A1, BL0);
                }
                {
                    v8bf BH1 = *(const v8bf*)(hib + 256 + llo*16);
                    v8bf BL1 = *(const v8bf*)(hib + 16384 + 256 + llo*16);
                    MFMA_(acc1[0][1], A0, BH1); MFMA_(acc1[0][1], A0, BL1);
                    MFMA_(acc1[1][1], A1, BH1); MFMA_(acc1[1][1], A1, BL1);
                }
            }
            __syncthreads();   // B3: U1 reads done

            // ACT L1 -> h1(step)
            #pragma unroll
            for (int nt=0;nt<2;nt++){
                unsigned short hh[2], hl[2];
                #pragma unroll
                for (int mi=0;mi<2;mi++){
                    float* cslot = (float*)(smb + C1O) + (mi*2+nt)*1024 + t;
                    f32x4 a = acc1[mi][nt];
                    float ii = fsig(a[0]), ff = fsig(a[1]), gg = ftanh(a[2]), oo = fsig(a[3]);
                    float c = ff*cslot[0] + ii*gg;
                    cslot[0] = c;
                    float h = oo*ftanh(c);
                    hh[mi] = f2bf(h);
                    hl[mi] = f2bf(h - bf2f(hh[mi]));
                }
                unsigned ph = (unsigned)hh[0] | ((unsigned)hh[1]<<16);
                unsigned pl = (unsigned)hl[0] | ((unsigned)hl[1]<<16);
                int bo = (16+j8)*512 + (nt*16+llo)*16 + sub;
                *(unsigned*)(smb + U1O + bo)         = ph;
                *(unsigned*)(smb + U1O + 16384 + bo) = pl;
            }
        }

        // ---- step 27: build decoder mean input into BOTH XB buffers
        if (step == DD-1){
            __syncthreads();
            if (t < 288){
                const float* xs = (const float*)(smb + X2O);
                __align__(16) unsigned short hb8[8], lb8[8];
                #pragma unroll
                for (int e=0;e<8;e++){
                    float v = xs[e*288+t] * (1.f/(float)DD);
                    unsigned short h = f2bf(v);
                    hb8[e] = h;
                    lb8[e] = f2bf(v - bf2f(h));
                }
                *(uint4*)(smb + XB0O + t*16)        = *(const uint4*)hb8;
                *(uint4*)(smb + XB0O + 4608 + t*16) = *(const uint4*)lb8;
                *(uint4*)(smb + XB1O + t*16)        = *(const uint4*)hb8;
                *(uint4*)(smb + XB1O + 4608 + t*16) = *(const uint4*)lb8;
            }
            __syncthreads();   // mean visible before step-28 L0 reads
        }

        // ---- decoder FC
        if (step >= DD){
            __syncthreads();   // h1 visible
            if (t < 256){
                int seq = t>>3, l8 = t&7;
                const unsigned short* uh = (const unsigned short*)(smb+U1O);
                const unsigned short* ul = (const unsigned short*)(smb+U1O+16384);
                const float* fw = (const float*)(smb+FCO);
                float a = 0.f;
                #pragma unroll
                for (int half=0; half<2; ++half){
                    int k8 = 16 + l8*2 + half;
                    int base = (k8*32 + seq)*8;
                    #pragma unroll
                    for (int e=0;e<8;e++){
                        int j = l8*16 + half*8 + e;
                        a = fmaf(fw[j], bf2f(uh[base+e]) + bf2f(ul[base+e]), a);
                    }
                }
                a += __shfl_down(a, 4, 8);
                a += __shfl_down(a, 2, 8);
                a += __shfl_down(a, 1, 8);
                if (l8 == 0){
                    int gseq = blk*32 + seq, n = gseq>>8, bb = gseq&255;
                    float yv = fmaxf(a + ((const float*)(smb+INO))[seq] + fw[128], 0.f);
                    __builtin_nontemporal_store(yv, &outy[((size_t)bb*DY + (step-DD))*DN + n]);
                }
            }
        }
        // no closing barrier for encoder steps (R7-proven scheme)
    }
}

// ---------------------------------------------------------------------------
extern "C" void kernel_launch(void* const* d_in, const int* in_sizes, int n_in,
                              void* d_out, int out_size, void* d_ws, size_t ws_size,
                              hipStream_t stream)
{
    const float* x         = (const float*)d_in[0];
    const float* adj_real  = (const float*)d_in[1];
    const float* infection = (const float*)d_in[2];
    const int*   day_order = (const int*)  d_in[3];
    const float* gl_w1     = (const float*)d_in[4];
    const float* gl_b1     = (const float*)d_in[5];
    const float* gl_w2     = (const float*)d_in[6];
    const float* gl_b2     = (const float*)d_in[7];
    const float* glp       = (const float*)d_in[8];
    const float* gcn_w     = (const float*)d_in[9];
    const float* vvec      = (const float*)d_in[10];
    const float* wih0      = (const float*)d_in[11];
    const float* whh0      = (const float*)d_in[12];
    const float* b0        = (const float*)d_in[13];
    const float* wih1      = (const float*)d_in[14];
    const float* whh1      = (const float*)d_in[15];
    const float* b1        = (const float*)d_in[16];
    const float* fcw       = (const float*)d_in[17];
    const float* fcb       = (const float*)d_in[18];

    uint8_t* wsb = (uint8_t*)d_ws;
    uint4*          zlin = (uint4*)(wsb);
    unsigned short* wb0  = (unsigned short*)(wsb + WB0_OFF);
    unsigned short* wb1  = (unsigned short*)(wsb + WB1_OFF);
    unsigned short* wpk  = (unsigned short*)(wsb + WPK_OFF);
    unsigned short* gpk  = (unsigned short*)(wsb + GPK_OFF);
    float* out_adj = (float*)d_out;
    float* out_y   = out_adj + ADJSZ;

    kernPrep<<<dim3(1248), dim3(256), 0, stream>>>(wih0, whh0, wih1, whh1,
                                                   gl_w1, gl_w2, gcn_w,
                                                   wb0, wb1, wpk, gpk);
    kernA<<<dim3(DB*DD), dim3(256), 0, stream>>>(x, adj_real, infection, day_order,
                                                 gl_b1, gl_b2, glp, vvec,
                                                 (const v8bf*)wpk, (const v8bf*)gpk,
                                                 out_adj, zlin);
    kernB<<<dim3(GBLK), dim3(1024), 0, stream>>>(zlin, (const v8bf*)wb0,
                                                 (const v8bf*)wb1, b0, b1, infection,
                                                 fcw, fcb, out_y);
}

// Round 12
// 552.816 us; speedup vs baseline: 1.2639x; 1.1642x over previous
//
#include <hip/hip_runtime.h>
#include <hip/hip_bf16.h>
#include <stdint.h>

// ---------------------------------------------------------------------------
// B=256 D=28 N=23 F=128 O=64 H=128 Y=7.  NBSEQ=5888 = 184 blocks x 32 seqs.
// R12: kernB = R11 (1024 thr, 16 waves, 4/SIMD, c-states in LDS) with the two
//      kt loops pinned to #pragma unroll 1.  Rationale: VGPR cap on this
//      toolchain = 65536/(waves per block) (256@256thr, 128@512thr, 64@1024thr)
//      and full unroll lets the scheduler hoist multiple kt iterations of
//      weight+LDS fragments (~12 regs/kt) past any cap -> persistent spills
//      (R7 34MB @128, R11 42MB+433MB HBM @64).  unroll 1 = one-iteration
//      prefetch window; 4 waves/SIMD hides the latency instead.
//      kernA/kernPrep unchanged (R9 MFMA versions).
// ---------------------------------------------------------------------------

#define DB 256
#define DD 28
#define DN 23
#define DF 128
#define DO 64
#define DH 128
#define DY 7
#define NBSEQ (DN*DB)
#define ADJSZ (DB*DD*DN*DN)
#define GBLK 184

// workspace byte offsets
#define WB0_OFF   47480832u            // zlin = 7168*414*16
#define WB1_OFF   47710208u
#define WPK_OFF   47972352u
#define GPK_OFF   48103424u

using v8bf  = __attribute__((ext_vector_type(8))) __bf16;
using f32x4 = __attribute__((ext_vector_type(4))) float;
using u32x4 = __attribute__((ext_vector_type(4))) unsigned int;

__device__ __forceinline__ float fsig(float x)  { return 1.f/(1.f+__expf(-x)); }
__device__ __forceinline__ float ftanh(float x) { return 1.f - 2.f/(__expf(2.f*x)+1.f); }

__device__ __forceinline__ unsigned short f2bf(float f){
    unsigned u = __builtin_bit_cast(unsigned, f);
    return (unsigned short)((u + 0x7FFFu + ((u>>16)&1u)) >> 16);
}
__device__ __forceinline__ float bf2f(unsigned short b){
    return __builtin_bit_cast(float, (unsigned)b << 16);
}
__device__ __forceinline__ uint4 ntload4(const uint4* p){
    u32x4 v = __builtin_nontemporal_load((const u32x4*)p);
    return *(uint4*)&v;
}

#define MFMA_(acc_, A_, B_) acc_ = __builtin_amdgcn_mfma_f32_16x16x32_bf16(A_, B_, acc_, 0, 0, 0)

// ---------------------------------------------------------------------------
// Prep (unchanged R9)
// ---------------------------------------------------------------------------
__global__ __launch_bounds__(256) void kernPrep(
    const float* __restrict__ wih0, const float* __restrict__ whh0,
    const float* __restrict__ wih1, const float* __restrict__ whh1,
    const float* __restrict__ glw1, const float* __restrict__ glw2,
    const float* __restrict__ gcn_w,
    unsigned short* __restrict__ wb0, unsigned short* __restrict__ wb1,
    unsigned short* __restrict__ wpk, unsigned short* __restrict__ gpk)
{
    int idx = blockIdx.x*256 + threadIdx.x;
    if (idx < 114688){
        int e = idx&7, l = (idx>>3)&63, mt = (idx>>9)&31, kt = idx>>14;
        int rit = l&15, lj = rit>>2, g = rit&3;
        int r = g*128 + (mt>>2)*16 + lj*4 + (mt&3);
        int k = kt*32 + (l>>4)*8 + e;
        float v = 0.f;
        if (k < 65)                  v = wih0[r*65 + k];
        else if (k >= 72 && k < 200) v = whh0[r*128 + (k-72)];
        wb0[idx] = f2bf(v);
        return;
    }
    idx -= 114688;
    if (idx < 131072){
        int e = idx&7, l = (idx>>3)&63, mt = (idx>>9)&31, kt = idx>>14;
        int rit = l&15, lj = rit>>2, g = rit&3;
        int r = g*128 + (mt>>2)*16 + lj*4 + (mt&3);
        int k = kt*32 + (l>>4)*8 + e;
        float v = (k < 128) ? wih1[r*128 + k] : whh1[r*128 + (k-128)];
        wb1[idx] = f2bf(v);
        return;
    }
    idx -= 131072;
    if (idx < 65536){
        int e = idx&7, l = (idx>>3)&63, hsel = (idx>>9)&1, kt = (idx>>10)&3,
            nt = (idx>>12)&7, mat = (idx>>15)&1;
        int fo = nt*16 + (l&15);
        int k  = kt*32 + (l>>4)*8 + e;
        float v = (mat ? glw2 : glw1)[fo*128 + k];
        unsigned short hb = f2bf(v);
        wpk[idx] = hsel ? f2bf(v - bf2f(hb)) : hb;
        return;
    }
    idx -= 65536;
    if (idx < 8192){
        int e = idx&7, l = (idx>>3)&63, kt = (idx>>9)&3, nt = (idx>>11)&3;
        int o = nt*16 + (l&15);
        int k = kt*32 + (l>>4)*8 + e;
        gpk[idx] = f2bf(gcn_w[k*64 + o]);
    }
}

// ---------------------------------------------------------------------------
// Kernel A (unchanged R9): per-(b,d) graph stage -> adj + zlin[bd][414].
// ---------------------------------------------------------------------------
__global__ __launch_bounds__(256) void kernA(
    const float* __restrict__ x, const float* __restrict__ adj_real,
    const float* __restrict__ infection, const int* __restrict__ day_order,
    const float* __restrict__ b1, const float* __restrict__ b2,
    const float* __restrict__ glp, const float* __restrict__ vvec,
    const v8bf* __restrict__ wpk, const v8bf* __restrict__ gpk,
    float* __restrict__ out_adj, uint4* __restrict__ zlin4)
{
    const int bd = blockIdx.x;
    const int b  = bd / DD;
    const int t  = threadIdx.x;
    const int w  = t>>6, l = t&63;

    __shared__ float sm[8740];
    const int N1=0, N2=3036, S12=6072, ADJ=6624, XW=7176, DEG=8648,
              DINV=8671, FACT=8694, INFS=8717;
    const int GC = N1;
    __shared__ __align__(16) unsigned short xhl[2][32][140];

    const float* xg = x + (size_t)bd*(DN*DF);
    for (int p=t; p<DN*DF; p+=256){
        int n = p>>7, k = p&127;
        float v = xg[p];
        unsigned short hb = f2bf(v);
        xhl[0][n][k] = hb;
        xhl[1][n][k] = f2bf(v - bf2f(hb));
    }
    for (int p=t; p<9*DF; p+=256){
        int n = DN + (p>>7), k = p&127;
        xhl[0][n][k] = 0; xhl[1][n][k] = 0;
    }
    if (t < DN){
        float vv = vvec[t];
        sm[FACT+t] = __expf(vv*vv*(float)day_order[b]);
        sm[INFS+t] = infection[(size_t)bd*DN + t];
    }
    __syncthreads();

    {
        const int mat = w>>1;
        const int ntb = (w&1)*4;
        const float* bsrc = mat ? b2 : b1;
        float bias[4];
        #pragma unroll
        for (int q=0;q<4;q++) bias[q] = bsrc[(ntb+q)*16 + (l&15)];
        f32x4 acc[2][4];
        #pragma unroll
        for (int mt=0;mt<2;mt++)
            #pragma unroll
            for (int q=0;q<4;q++){ f32x4 z; z[0]=z[1]=z[2]=z[3]=0.f; acc[mt][q]=z; }
        #pragma unroll
        for (int kt=0;kt<4;kt++){
            v8bf ah[2], al[2];
            #pragma unroll
            for (int mt=0;mt<2;mt++){
                int m = mt*16 + (l&15);
                int ko = (l>>4)*8 + kt*32;
                ah[mt] = *(const v8bf*)&xhl[0][m][ko];
                al[mt] = *(const v8bf*)&xhl[1][m][ko];
            }
            #pragma unroll
            for (int q=0;q<4;q++){
                const v8bf* wb = wpk + ((size_t)(((mat*8+(ntb+q))*4+kt)*2)*64 + l);
                v8bf wh = wb[0], wl = wb[64];
                MFMA_(acc[0][q], ah[0], wh);
                MFMA_(acc[1][q], ah[1], wh);
                MFMA_(acc[0][q], al[0], wh);
                MFMA_(acc[1][q], al[1], wh);
                MFMA_(acc[0][q], ah[0], wl);
                MFMA_(acc[1][q], ah[1], wl);
            }
        }
        const int dst = mat ? N2 : N1;
        #pragma unroll
        for (int mt=0;mt<2;mt++){
            #pragma unroll
            for (int q=0;q<4;q++){
                int fo = (ntb+q)*16 + (l&15);
                #pragma unroll
                for (int r=0;r<4;r++){
                    int n = mt*16 + (l>>4)*4 + r;
                    if (n < DN) sm[dst + n*132 + fo] = ftanh(acc[mt][q][r] + bias[q]);
                }
            }
        }
    }
    __syncthreads();

    if (t < DN){
        const float* ar = adj_real + (size_t)bd*(DN*DN) + t*DN;
        float s = 0.f;
        for (int m=0;m<DN;m++) s += ar[m];
        sm[DEG+t] = s;
    }
    for (int p=t; p<DN*DN; p+=256){
        int i = p/DN, j = p - i*DN;
        float a = 0.f;
        for (int k4=0;k4<32;k4++){
            const float4 av = *(const float4*)&sm[N1 + i*132 + 4*k4];
            const float4 bv = *(const float4*)&sm[N2 + j*132 + 4*k4];
            a = fmaf(av.w,bv.w, fmaf(av.z,bv.z, fmaf(av.y,bv.y, fmaf(av.x,bv.x,a))));
        }
        sm[S12 + i*24 + j] = a;
    }
    __syncthreads();

    for (int p=t; p<DN*DN; p+=256){
        int i=p/DN, j=p-i*DN;
        float al  = fmaxf(ftanh(sm[S12+i*24+j]-sm[S12+j*24+i]), 0.f);
        float md  = fsig(glp[i*DN+j]*sm[DEG+i]*sm[DEG+j]);
        float arv = adj_real[(size_t)bd*(DN*DN) + p];
        float adjv = al + md*arv;
        __builtin_nontemporal_store(adjv, &out_adj[(size_t)bd*(DN*DN) + p]);
        sm[ADJ + i*24 + j] = adjv + (i==j ? 1.f : 0.f);
    }
    __syncthreads();

    if (t<DN){
        float rs=0.f;
        for (int jj=0;jj<DN;jj++) rs += sm[ADJ+t*24+jj];
        sm[DINV+t] = rsqrtf(rs);
    }
    __syncthreads();

    for (int p=t;p<DN*DN;p+=256){
        int i=p/DN, j=p-i*DN;
        sm[ADJ+i*24+j] *= sm[DINV+i]*sm[DINV+j];
    }
    {
        f32x4 acc2[2];
        { f32x4 z; z[0]=z[1]=z[2]=z[3]=0.f; acc2[0]=z; acc2[1]=z; }
        #pragma unroll
        for (int kt=0;kt<4;kt++){
            v8bf ah[2], al[2];
            #pragma unroll
            for (int mt=0;mt<2;mt++){
                int m = mt*16 + (l&15);
                int ko = (l>>4)*8 + kt*32;
                ah[mt] = *(const v8bf*)&xhl[0][m][ko];
                al[mt] = *(const v8bf*)&xhl[1][m][ko];
            }
            v8bf gh = gpk[(size_t)(w*4+kt)*64 + l];
            MFMA_(acc2[0], ah[0], gh);
            MFMA_(acc2[1], ah[1], gh);
            MFMA_(acc2[0], al[0], gh);
            MFMA_(acc2[1], al[1], gh);
        }
        int o = w*16 + (l&15);
        #pragma unroll
        for (int mt=0;mt<2;mt++){
            #pragma unroll
            for (int r=0;r<4;r++){
                int n = mt*16 + (l>>4)*4 + r;
                if (n < DN) sm[XW + n*64 + o] = acc2[mt][r];
            }
        }
    }
    __syncthreads();

    for (int p=t;p<DN*64;p+=256){
        int n=p>>6, o=p&63;
        float a=0.f;
        #pragma unroll
        for (int m=0;m<DN;m++) a = fmaf(sm[ADJ+n*24+m], sm[XW+m*64+o], a);
        sm[GC + p] = fmaxf(a,0.f)*sm[FACT+n];
    }
    __syncthreads();

    for (int p=t; p<DN*18; p+=256){
        int n = p/18, r = p - n*18, hsel = r/9, k8 = r - hsel*9;
        __align__(16) unsigned short ob[8];
        #pragma unroll
        for (int e=0;e<8;e++){
            int k = k8*8+e;
            float v = (k<64) ? sm[GC + n*64 + k] : ((k==64) ? sm[INFS+n] : 0.f);
            unsigned short hb = f2bf(v);
            ob[e] = hsel ? f2bf(v - bf2f(hb)) : hb;
        }
        zlin4[(size_t)bd*414 + p] = *(const uint4*)ob;
    }
}

// ---------------------------------------------------------------------------
// Kernel B: MFMA LSTM.  grid=184, block=1024 (16 waves), 32 seqs/block.
// Wave w: M-tiles 2w, 2w+1.  acc[2][2]=16 VGPR; c-states in LDS slots;
// kt loops at #pragma unroll 1 (single-iteration prefetch window -> fits the
// 64-VGPR cap the toolchain grants 1024-thread blocks; 4 waves/SIMD hide
// the serialized load latency).
// ---------------------------------------------------------------------------
#define XB0O 0
#define XB1O 9216
#define H0O  18432          // hi 19x512 = 9728 ; lo at +9728
#define U1O  37888          // hi 32x512 = 16384 ; lo at +16384
#define X2O  70656          // [8][288] f32 = 9216
#define B0O  79872          // 512 f32
#define B1O  81920
#define FCO  83968          // 129 f32
#define INO  84488          // 32 f32
#define C0O  84624          // 4 slots x 1024 f32 = 16384
#define C1O  101008         // 16384
// end 117392

__global__ __launch_bounds__(1024, 2) void kernB(
    const uint4* __restrict__ zlin, const v8bf* __restrict__ w0p, const v8bf* __restrict__ w1p,
    const float* __restrict__ b0g, const float* __restrict__ b1g,
    const float* __restrict__ infection, const float* __restrict__ fcw,
    const float* __restrict__ fcb, float* __restrict__ outy)
{
    const int t = threadIdx.x, blk = blockIdx.x;
    const int w = t>>6, l = t&63;
    const int lhi = l>>4, llo = l&15;
    __shared__ __align__(16) unsigned char smraw[117392];
    char* smb = (char*)smraw;

    // zero H0..X2 end (18432..79872) and c-slots (84624..117392)
    {
        uint4 z; z.x=z.y=z.z=z.w=0u;
        for (int i = t; i < (79872-18432)/16; i += 1024) ((uint4*)(smb+18432))[i] = z;
        for (int i = t; i < (117392-84624)/16; i += 1024) ((uint4*)(smb+84624))[i] = z;
    }
    if (t < 512){
        ((float*)(smb+B0O))[t] = b0g[t];
        ((float*)(smb+B1O))[t] = b1g[t];
    }
    if (t < 129) ((float*)(smb+FCO))[t] = (t<128) ? fcw[t] : fcb[0];
    if (t < 32){
        int gseq = blk*32 + t, n = gseq>>8, bb = gseq&255;
        float a = 0.f;
        for (int dd=0; dd<DD; dd++)
            a = fmaf(fcw[128+dd], infection[((size_t)bb*DD+dd)*DN+n], a);
        ((float*)(smb+INO))[t] = a;
    }

    // staging constants (t<576: unit u = t)
    int hs1 = (t >= 288) ? 1 : 0;  int rm1 = t - hs1*288;
    int k81 = rm1 >> 5, sq1 = rm1 & 31;
    int gs1 = blk*32 + sq1;
    size_t cb1 = (size_t)(gs1 & 255)*DD*414 + (gs1>>8)*18 + hs1*9 + k81;
    int d1 = t*16;

    // output-tile constants
    const int mt0 = 2*w;
    const int jt  = mt0>>2, r3 = mt0&3;
    const int j8  = jt*2 + (lhi>>1);
    const int sub = (lhi&1)*8 + r3*2;
    const int j0  = jt*16 + lhi*4 + r3;

    __syncthreads();

    // prologue: stage x(0) into XB0
    if (t < 576){
        uint4 a0 = ntload4(zlin + cb1);
        *(uint4*)(smb + XB0O + d1) = a0;
    }
    __syncthreads();

    const float* bias0L = (const float*)(smb+B0O);
    const float* bias1L = (const float*)(smb+B1O);

    for (int step = 0; step < DD + DY; ++step){
        const int xb  = (step & 1) ? XB1O : XB0O;
        const int xbn = (step & 1) ? XB0O : XB1O;
        const bool do_stage = (step + 1 < DD);

        // ---------------- L0 MFMA (+ stage x(step+1)) ----------------
        {
            uint4 sv0; sv0.x=sv0.y=sv0.z=sv0.w=0u;
            if (do_stage && t < 576)
                sv0 = ntload4(zlin + (size_t)(step+1)*414 + cb1);

            f32x4 acc[2][2];
            #pragma unroll
            for (int mi=0;mi<2;mi++){
                int j = j0 + mi;
                f32x4 a;
                a[0]=bias0L[j]; a[1]=bias0L[128+j]; a[2]=bias0L[256+j]; a[3]=bias0L[384+j];
                acc[mi][0] = a; acc[mi][1] = a;
            }
            #pragma unroll 1
            for (int kt=0; kt<7; ++kt){
                const v8bf* wrow = w0p + (size_t)(kt*32 + mt0)*64 + l;
                v8bf A0 = wrow[0], A1 = wrow[64];
                int k8 = kt*4 + lhi;
                bool inx = (k8 <= 8);
                const char* hib = inx ? (smb + xb + k8*512) : (smb + H0O + (k8-9)*512);
                int losh = inx ? 4608 : 9728;
                {   // half-round 0: nt=0 fragments only
                    v8bf BH0 = *(const v8bf*)(hib + llo*16);
                    v8bf BL0 = *(const v8bf*)(hib + losh + llo*16);
                    MFMA_(acc[0][0], A0, BH0); MFMA_(acc[0][0], A0, BL0);
                    MFMA_(acc[1][0], A1, BH0); MFMA_(acc[1][0], A1, BL0);
                }
                {   // half-round 1: nt=1 fragments
                    v8bf BH1 = *(const v8bf*)(hib + 256 + llo*16);
                    v8bf BL1 = *(const v8bf*)(hib + losh + 256 + llo*16);
                    MFMA_(acc[0][1], A0, BH1); MFMA_(acc[0][1], A0, BL1);
                    MFMA_(acc[1][1], A1, BH1); MFMA_(acc[1][1], A1, BL1);
                }
            }
            if (do_stage && t < 576)
                *(uint4*)(smb + xbn + d1) = sv0;
            __syncthreads();   // B1: xb/H0 reads done

            // x2 accumulation of x(step)
            if (step < DD && t < 288){
                const unsigned short* hp = (const unsigned short*)(smb + xb + t*16);
                const unsigned short* lp = (const unsigned short*)(smb + xb + 4608 + t*16);
                float* xs = (float*)(smb + X2O);
                #pragma unroll
                for (int e=0;e<8;e++) xs[e*288+t] += bf2f(hp[e]) + bf2f(lp[e]);
            }

            // ACT L0 -> h0(step); c in LDS slots
            #pragma unroll
            for (int nt=0;nt<2;nt++){
                unsigned short hh[2], hl[2];
                #pragma unroll
                for (int mi=0;mi<2;mi++){
                    float* cslot = (float*)(smb + C0O) + (mi*2+nt)*1024 + t;
                    f32x4 a = acc[mi][nt];
                    float ii = fsig(a[0]), ff = fsig(a[1]), gg = ftanh(a[2]), oo = fsig(a[3]);
                    float c = ff*cslot[0] + ii*gg;
                    cslot[0] = c;
                    float h = oo*ftanh(c);
                    hh[mi] = f2bf(h);
                    hl[mi] = f2bf(h - bf2f(hh[mi]));
                }
                unsigned ph = (unsigned)hh[0] | ((unsigned)hh[1]<<16);
                unsigned pl = (unsigned)hl[0] | ((unsigned)hl[1]<<16);
                int bo = j8*512 + (nt*16+llo)*16 + sub;
                *(unsigned*)(smb + H0O + bo)         = ph;
                *(unsigned*)(smb + H0O + 9728 + bo)  = pl;
                *(unsigned*)(smb + U1O + bo)         = ph;
                *(unsigned*)(smb + U1O + 16384 + bo) = pl;
            }
            __syncthreads();   // B2: h0 visible
        }

        // ---------------- L1 MFMA ----------------
        {
            f32x4 acc1[2][2];
            #pragma unroll
            for (int mi=0;mi<2;mi++){
                int j = j0 + mi;
                f32x4 a;
                a[0]=bias1L[j]; a[1]=bias1L[128+j]; a[2]=bias1L[256+j]; a[3]=bias1L[384+j];
                acc1[mi][0] = a; acc1[mi][1] = a;
            }
            #pragma unroll 1
            for (int kt=0; kt<8; ++kt){
                const v8bf* wrow = w1p + (size_t)(kt*32 + mt0)*64 + l;
                v8bf A0 = wrow[0], A1 = wrow[64];
                const char* hib = smb + U1O + (kt*4+lhi)*512;
                {
                    v8bf BH0 = *(const v8bf*)(hib + llo*16);
                    v8bf BL0 = *(const v8bf*)(hib + 16384 + llo*16);
                    MFMA_(acc1[0][0], A0, BH0); MFMA_(acc1[0][0], A0, BL0);
                    MFMA_(acc1[1][0], A1, BH0); MFMA_(acc1[1][0], A1, BL0);
                }
                {
                    v8bf BH1 = *(const v8bf*)(hib + 256 + llo*16);
                    v8bf BL1 = *(const v8bf*)(hib + 16384 + 256 + llo*16);
                    MFMA_(acc1[0][1], A0, BH1); MFMA_(acc1[0][1], A0, BL1);
                    MFMA_(acc1[1][1], A1, BH1); MFMA_(acc1[1][1], A1, BL1);
                }
            }
            __syncthreads();   // B3: U1 reads done

            // ACT L1 -> h1(step)
            #pragma unroll
            for (int nt=0;nt<2;nt++){
                unsigned short hh[2], hl[2];
                #pragma unroll
                for (int mi=0;mi<2;mi++){
                    float* cslot = (float*)(smb + C1O) + (mi*2+nt)*1024 + t;
                    f32x4 a = acc1[mi][nt];
                    float ii = fsig(a[0]), ff = fsig(a[1]), gg = ftanh(a[2]), oo = fsig(a[3]);
                    float c = ff*cslot[0] + ii*gg;
                    cslot[0] = c;
                    float h = oo*ftanh(c);
                    hh[mi] = f2bf(h);
                    hl[mi] = f2bf(h - bf2f(hh[mi]));
                }
                unsigned ph = (unsigned)hh[0] | ((unsigned)hh[1]<<16);
                unsigned pl = (unsigned)hl[0] | ((unsigned)hl[1]<<16);
                int bo = (16+j8)*512 + (nt*16+llo)*16 + sub;
                *(unsigned*)(smb + U1O + bo)         = ph;
                *(unsigned*)(smb + U1O + 16384 + bo) = pl;
            }
        }

        // ---- step 27: build decoder mean input into BOTH XB buffers
        if (step == DD-1){
            __syncthreads();
            if (t < 288){
                const float* xs = (const float*)(smb + X2O);
                __align__(16) unsigned short hb8[8], lb8[8];
                #pragma unroll
                for (int e=0;e<8;e++){
                    float v = xs[e*288+t] * (1.f/(float)DD);
                    unsigned short h = f2bf(v);
                    hb8[e] = h;
                    lb8[e] = f2bf(v - bf2f(h));
                }
                *(uint4*)(smb + XB0O + t*16)        = *(const uint4*)hb8;
                *(uint4*)(smb + XB0O + 4608 + t*16) = *(const uint4*)lb8;
                *(uint4*)(smb + XB1O + t*16)        = *(const uint4*)hb8;
                *(uint4*)(smb + XB1O + 4608 + t*16) = *(const uint4*)lb8;
            }
            __syncthreads();   // mean visible before step-28 L0 reads
        }

        // ---- decoder FC
        if (step >= DD){
            __syncthreads();   // h1 visible
            if (t < 256){
                int seq = t>>3, l8 = t&7;
                const unsigned short* uh = (const unsigned short*)(smb+U1O);
                const unsigned short* ul = (const unsigned short*)(smb+U1O+16384);
                const float* fw = (const float*)(smb+FCO);
                float a = 0.f;
                #pragma unroll
                for (int half=0; half<2; ++half){
                    int k8 = 16 + l8*2 + half;
                    int base = (k8*32 + seq)*8;
                    #pragma unroll
                    for (int e=0;e<8;e++){
                        int j = l8*16 + half*8 + e;
                        a = fmaf(fw[j], bf2f(uh[base+e]) + bf2f(ul[base+e]), a);
                    }
                }
                a += __shfl_down(a, 4, 8);
                a += __shfl_down(a, 2, 8);
                a += __shfl_down(a, 1, 8);
                if (l8 == 0){
                    int gseq = blk*32 + seq, n = gseq>>8, bb = gseq&255;
                    float yv = fmaxf(a + ((const float*)(smb+INO))[seq] + fw[128], 0.f);
                    __builtin_nontemporal_store(yv, &outy[((size_t)bb*DY + (step-DD))*DN + n]);
                }
            }
        }
        // no closing barrier for encoder steps (R7-proven scheme)
    }
}

// ---------------------------------------------------------------------------
extern "C" void kernel_launch(void* const* d_in, const int* in_sizes, int n_in,
                              void* d_out, int out_size, void* d_ws, size_t ws_size,
                              hipStream_t stream)
{
    const float* x         = (const float*)d_in[0];
    const float* adj_real  = (const float*)d_in[1];
    const float* infection = (const float*)d_in[2];
    const int*   day_order = (const int*)  d_in[3];
    const float* gl_w1     = (const float*)d_in[4];
    const float* gl_b1     = (const float*)d_in[5];
    const float* gl_w2     = (const float*)d_in[6];
    const float* gl_b2     = (const float*)d_in[7];
    const float* glp       = (const float*)d_in[8];
    const float* gcn_w     = (const float*)d_in[9];
    const float* vvec      = (const float*)d_in[10];
    const float* wih0      = (const float*)d_in[11];
    const float* whh0      = (const float*)d_in[12];
    const float* b0        = (const float*)d_in[13];
    const float* wih1      = (const float*)d_in[14];
    const float* whh1      = (const float*)d_in[15];
    const float* b1        = (const float*)d_in[16];
    const float* fcw       = (const float*)d_in[17];
    const float* fcb       = (const float*)d_in[18];

    uint8_t* wsb = (uint8_t*)d_ws;
    uint4*          zlin = (uint4*)(wsb);
    unsigned short* wb0  = (unsigned short*)(wsb + WB0_OFF);
    unsigned short* wb1  = (unsigned short*)(wsb + WB1_OFF);
    unsigned short* wpk  = (unsigned short*)(wsb + WPK_OFF);
    unsigned short* gpk  = (unsigned short*)(wsb + GPK_OFF);
    float* out_adj = (float*)d_out;
    float* out_y   = out_adj + ADJSZ;

    kernPrep<<<dim3(1248), dim3(256), 0, stream>>>(wih0, whh0, wih1, whh1,
                                                   gl_w1, gl_w2, gcn_w,
                                                   wb0, wb1, wpk, gpk);
    kernA<<<dim3(DB*DD), dim3(256), 0, stream>>>(x, adj_real, infection, day_order,
                                                 gl_b1, gl_b2, glp, vvec,
                                                 (const v8bf*)wpk, (const v8bf*)gpk,
                                                 out_adj, zlin);
    kernB<<<dim3(GBLK), dim3(1024), 0, stream>>>(zlin, (const v8bf*)wb0,
                                                 (const v8bf*)wb1, b0, b1, infection,
                                                 fcw, fcb, out_y);
}

// Round 13
// 495.884 us; speedup vs baseline: 1.4090x; 1.1148x over previous
//
#include <hip/hip_runtime.h>
#include <hip/hip_bf16.h>
#include <stdint.h>

// ---------------------------------------------------------------------------
// B=256 D=28 N=23 F=128 O=64 H=128 Y=7.  NBSEQ=5888 = 184 blocks x 32 seqs.
// R13: kernB drops the lo-compensation stream (hi-only bf16 B operands).
//      Rationale: absmax has been pinned at 2^-7 (bf16-ref rounding floor)
//      since the all-f32 R1 -> the hi+lo path is unmeasured overkill.
//      Halves MFMA count (120->60/wave/step), B-frag ds_reads, h ds_writes,
//      zin staging (576->288 threads), and the f2bf-lo VALU work.
//      c-state stays f32 in LDS (integrator exact).
//      R12's unroll-1 kt loops kept (spill fix: VGPR 52, WRITE 2.8MB).
//      kernA/kernPrep unchanged (R9 MFMA versions).
// ---------------------------------------------------------------------------

#define DB 256
#define DD 28
#define DN 23
#define DF 128
#define DO 64
#define DH 128
#define DY 7
#define NBSEQ (DN*DB)
#define ADJSZ (DB*DD*DN*DN)
#define GBLK 184

// workspace byte offsets
#define WB0_OFF   47480832u            // zlin = 7168*414*16
#define WB1_OFF   47710208u
#define WPK_OFF   47972352u
#define GPK_OFF   48103424u

using v8bf  = __attribute__((ext_vector_type(8))) __bf16;
using f32x4 = __attribute__((ext_vector_type(4))) float;
using u32x4 = __attribute__((ext_vector_type(4))) unsigned int;

__device__ __forceinline__ float fsig(float x)  { return 1.f/(1.f+__expf(-x)); }
__device__ __forceinline__ float ftanh(float x) { return 1.f - 2.f/(__expf(2.f*x)+1.f); }

__device__ __forceinline__ unsigned short f2bf(float f){
    unsigned u = __builtin_bit_cast(unsigned, f);
    return (unsigned short)((u + 0x7FFFu + ((u>>16)&1u)) >> 16);
}
__device__ __forceinline__ float bf2f(unsigned short b){
    return __builtin_bit_cast(float, (unsigned)b << 16);
}
__device__ __forceinline__ uint4 ntload4(const uint4* p){
    u32x4 v = __builtin_nontemporal_load((const u32x4*)p);
    return *(uint4*)&v;
}

#define MFMA_(acc_, A_, B_) acc_ = __builtin_amdgcn_mfma_f32_16x16x32_bf16(A_, B_, acc_, 0, 0, 0)

// ---------------------------------------------------------------------------
// Prep (unchanged R9)
// ---------------------------------------------------------------------------
__global__ __launch_bounds__(256) void kernPrep(
    const float* __restrict__ wih0, const float* __restrict__ whh0,
    const float* __restrict__ wih1, const float* __restrict__ whh1,
    const float* __restrict__ glw1, const float* __restrict__ glw2,
    const float* __restrict__ gcn_w,
    unsigned short* __restrict__ wb0, unsigned short* __restrict__ wb1,
    unsigned short* __restrict__ wpk, unsigned short* __restrict__ gpk)
{
    int idx = blockIdx.x*256 + threadIdx.x;
    if (idx < 114688){
        int e = idx&7, l = (idx>>3)&63, mt = (idx>>9)&31, kt = idx>>14;
        int rit = l&15, lj = rit>>2, g = rit&3;
        int r = g*128 + (mt>>2)*16 + lj*4 + (mt&3);
        int k = kt*32 + (l>>4)*8 + e;
        float v = 0.f;
        if (k < 65)                  v = wih0[r*65 + k];
        else if (k >= 72 && k < 200) v = whh0[r*128 + (k-72)];
        wb0[idx] = f2bf(v);
        return;
    }
    idx -= 114688;
    if (idx < 131072){
        int e = idx&7, l = (idx>>3)&63, mt = (idx>>9)&31, kt = idx>>14;
        int rit = l&15, lj = rit>>2, g = rit&3;
        int r = g*128 + (mt>>2)*16 + lj*4 + (mt&3);
        int k = kt*32 + (l>>4)*8 + e;
        float v = (k < 128) ? wih1[r*128 + k] : whh1[r*128 + (k-128)];
        wb1[idx] = f2bf(v);
        return;
    }
    idx -= 131072;
    if (idx < 65536){
        int e = idx&7, l = (idx>>3)&63, hsel = (idx>>9)&1, kt = (idx>>10)&3,
            nt = (idx>>12)&7, mat = (idx>>15)&1;
        int fo = nt*16 + (l&15);
        int k  = kt*32 + (l>>4)*8 + e;
        float v = (mat ? glw2 : glw1)[fo*128 + k];
        unsigned short hb = f2bf(v);
        wpk[idx] = hsel ? f2bf(v - bf2f(hb)) : hb;
        return;
    }
    idx -= 65536;
    if (idx < 8192){
        int e = idx&7, l = (idx>>3)&63, kt = (idx>>9)&3, nt = (idx>>11)&3;
        int o = nt*16 + (l&15);
        int k = kt*32 + (l>>4)*8 + e;
        gpk[idx] = f2bf(gcn_w[k*64 + o]);
    }
}

// ---------------------------------------------------------------------------
// Kernel A (unchanged R9): per-(b,d) graph stage -> adj + zlin[bd][414].
// ---------------------------------------------------------------------------
__global__ __launch_bounds__(256) void kernA(
    const float* __restrict__ x, const float* __restrict__ adj_real,
    const float* __restrict__ infection, const int* __restrict__ day_order,
    const float* __restrict__ b1, const float* __restrict__ b2,
    const float* __restrict__ glp, const float* __restrict__ vvec,
    const v8bf* __restrict__ wpk, const v8bf* __restrict__ gpk,
    float* __restrict__ out_adj, uint4* __restrict__ zlin4)
{
    const int bd = blockIdx.x;
    const int b  = bd / DD;
    const int t  = threadIdx.x;
    const int w  = t>>6, l = t&63;

    __shared__ float sm[8740];
    const int N1=0, N2=3036, S12=6072, ADJ=6624, XW=7176, DEG=8648,
              DINV=8671, FACT=8694, INFS=8717;
    const int GC = N1;
    __shared__ __align__(16) unsigned short xhl[2][32][140];

    const float* xg = x + (size_t)bd*(DN*DF);
    for (int p=t; p<DN*DF; p+=256){
        int n = p>>7, k = p&127;
        float v = xg[p];
        unsigned short hb = f2bf(v);
        xhl[0][n][k] = hb;
        xhl[1][n][k] = f2bf(v - bf2f(hb));
    }
    for (int p=t; p<9*DF; p+=256){
        int n = DN + (p>>7), k = p&127;
        xhl[0][n][k] = 0; xhl[1][n][k] = 0;
    }
    if (t < DN){
        float vv = vvec[t];
        sm[FACT+t] = __expf(vv*vv*(float)day_order[b]);
        sm[INFS+t] = infection[(size_t)bd*DN + t];
    }
    __syncthreads();

    {
        const int mat = w>>1;
        const int ntb = (w&1)*4;
        const float* bsrc = mat ? b2 : b1;
        float bias[4];
        #pragma unroll
        for (int q=0;q<4;q++) bias[q] = bsrc[(ntb+q)*16 + (l&15)];
        f32x4 acc[2][4];
        #pragma unroll
        for (int mt=0;mt<2;mt++)
            #pragma unroll
            for (int q=0;q<4;q++){ f32x4 z; z[0]=z[1]=z[2]=z[3]=0.f; acc[mt][q]=z; }
        #pragma unroll
        for (int kt=0;kt<4;kt++){
            v8bf ah[2], al[2];
            #pragma unroll
            for (int mt=0;mt<2;mt++){
                int m = mt*16 + (l&15);
                int ko = (l>>4)*8 + kt*32;
                ah[mt] = *(const v8bf*)&xhl[0][m][ko];
                al[mt] = *(const v8bf*)&xhl[1][m][ko];
            }
            #pragma unroll
            for (int q=0;q<4;q++){
                const v8bf* wb = wpk + ((size_t)(((mat*8+(ntb+q))*4+kt)*2)*64 + l);
                v8bf wh = wb[0], wl = wb[64];
                MFMA_(acc[0][q], ah[0], wh);
                MFMA_(acc[1][q], ah[1], wh);
                MFMA_(acc[0][q], al[0], wh);
                MFMA_(acc[1][q], al[1], wh);
                MFMA_(acc[0][q], ah[0], wl);
                MFMA_(acc[1][q], ah[1], wl);
            }
        }
        const int dst = mat ? N2 : N1;
        #pragma unroll
        for (int mt=0;mt<2;mt++){
            #pragma unroll
            for (int q=0;q<4;q++){
                int fo = (ntb+q)*16 + (l&15);
                #pragma unroll
                for (int r=0;r<4;r++){
                    int n = mt*16 + (l>>4)*4 + r;
                    if (n < DN) sm[dst + n*132 + fo] = ftanh(acc[mt][q][r] + bias[q]);
                }
            }
        }
    }
    __syncthreads();

    if (t < DN){
        const float* ar = adj_real + (size_t)bd*(DN*DN) + t*DN;
        float s = 0.f;
        for (int m=0;m<DN;m++) s += ar[m];
        sm[DEG+t] = s;
    }
    for (int p=t; p<DN*DN; p+=256){
        int i = p/DN, j = p - i*DN;
        float a = 0.f;
        for (int k4=0;k4<32;k4++){
            const float4 av = *(const float4*)&sm[N1 + i*132 + 4*k4];
            const float4 bv = *(const float4*)&sm[N2 + j*132 + 4*k4];
            a = fmaf(av.w,bv.w, fmaf(av.z,bv.z, fmaf(av.y,bv.y, fmaf(av.x,bv.x,a))));
        }
        sm[S12 + i*24 + j] = a;
    }
    __syncthreads();

    for (int p=t; p<DN*DN; p+=256){
        int i=p/DN, j=p-i*DN;
        float al  = fmaxf(ftanh(sm[S12+i*24+j]-sm[S12+j*24+i]), 0.f);
        float md  = fsig(glp[i*DN+j]*sm[DEG+i]*sm[DEG+j]);
        float arv = adj_real[(size_t)bd*(DN*DN) + p];
        float adjv = al + md*arv;
        __builtin_nontemporal_store(adjv, &out_adj[(size_t)bd*(DN*DN) + p]);
        sm[ADJ + i*24 + j] = adjv + (i==j ? 1.f : 0.f);
    }
    __syncthreads();

    if (t<DN){
        float rs=0.f;
        for (int jj=0;jj<DN;jj++) rs += sm[ADJ+t*24+jj];
        sm[DINV+t] = rsqrtf(rs);
    }
    __syncthreads();

    for (int p=t;p<DN*DN;p+=256){
        int i=p/DN, j=p-i*DN;
        sm[ADJ+i*24+j] *= sm[DINV+i]*sm[DINV+j];
    }
    {
        f32x4 acc2[2];
        { f32x4 z; z[0]=z[1]=z[2]=z[3]=0.f; acc2[0]=z; acc2[1]=z; }
        #pragma unroll
        for (int kt=0;kt<4;kt++){
            v8bf ah[2], al[2];
            #pragma unroll
            for (int mt=0;mt<2;mt++){
                int m = mt*16 + (l&15);
                int ko = (l>>4)*8 + kt*32;
                ah[mt] = *(const v8bf*)&xhl[0][m][ko];
                al[mt] = *(const v8bf*)&xhl[1][m][ko];
            }
            v8bf gh = gpk[(size_t)(w*4+kt)*64 + l];
            MFMA_(acc2[0], ah[0], gh);
            MFMA_(acc2[1], ah[1], gh);
            MFMA_(acc2[0], al[0], gh);
            MFMA_(acc2[1], al[1], gh);
        }
        int o = w*16 + (l&15);
        #pragma unroll
        for (int mt=0;mt<2;mt++){
            #pragma unroll
            for (int r=0;r<4;r++){
                int n = mt*16 + (l>>4)*4 + r;
                if (n < DN) sm[XW + n*64 + o] = acc2[mt][r];
            }
        }
    }
    __syncthreads();

    for (int p=t;p<DN*64;p+=256){
        int n=p>>6, o=p&63;
        float a=0.f;
        #pragma unroll
        for (int m=0;m<DN;m++) a = fmaf(sm[ADJ+n*24+m], sm[XW+m*64+o], a);
        sm[GC + p] = fmaxf(a,0.f)*sm[FACT+n];
    }
    __syncthreads();

    for (int p=t; p<DN*18; p+=256){
        int n = p/18, r = p - n*18, hsel = r/9, k8 = r - hsel*9;
        __align__(16) unsigned short ob[8];
        #pragma unroll
        for (int e=0;e<8;e++){
            int k = k8*8+e;
            float v = (k<64) ? sm[GC + n*64 + k] : ((k==64) ? sm[INFS+n] : 0.f);
            unsigned short hb = f2bf(v);
            ob[e] = hsel ? f2bf(v - bf2f(hb)) : hb;
        }
        zlin4[(size_t)bd*414 + p] = *(const uint4*)ob;
    }
}

// ---------------------------------------------------------------------------
// Kernel B: MFMA LSTM.  grid=184, block=1024 (16 waves), 32 seqs/block.
// Wave w: M-tiles 2w, 2w+1.  acc[2][2]=16 VGPR; c-states f32 in LDS slots;
// kt loops at unroll 1 (R12 spill fix).  HI-ONLY bf16 operands (R13):
// L0 = 7kt x 4 MFMA, L1 = 8kt x 4 MFMA; staging t<288 (x hi only).
// ---------------------------------------------------------------------------
#define XB0O 0
#define XB1O 9216
#define H0O  18432          // hi 19x512 (lo region unused)
#define U1O  37888          // hi 32x512 (lo region unused)
#define X2O  70656          // [8][288] f32 = 9216
#define B0O  79872          // 512 f32
#define B1O  81920
#define FCO  83968          // 129 f32
#define INO  84488          // 32 f32
#define C0O  84624          // 4 slots x 1024 f32 = 16384
#define C1O  101008         // 16384
// end 117392

__global__ __launch_bounds__(1024, 2) void kernB(
    const uint4* __restrict__ zlin, const v8bf* __restrict__ w0p, const v8bf* __restrict__ w1p,
    const float* __restrict__ b0g, const float* __restrict__ b1g,
    const float* __restrict__ infection, const float* __restrict__ fcw,
    const float* __restrict__ fcb, float* __restrict__ outy)
{
    const int t = threadIdx.x, blk = blockIdx.x;
    const int w = t>>6, l = t&63;
    const int lhi = l>>4, llo = l&15;
    __shared__ __align__(16) unsigned char smraw[117392];
    char* smb = (char*)smraw;

    // zero H0..X2 end (18432..79872) and c-slots (84624..117392)
    {
        uint4 z; z.x=z.y=z.z=z.w=0u;
        for (int i = t; i < (79872-18432)/16; i += 1024) ((uint4*)(smb+18432))[i] = z;
        for (int i = t; i < (117392-84624)/16; i += 1024) ((uint4*)(smb+84624))[i] = z;
    }
    if (t < 512){
        ((float*)(smb+B0O))[t] = b0g[t];
        ((float*)(smb+B1O))[t] = b1g[t];
    }
    if (t < 129) ((float*)(smb+FCO))[t] = (t<128) ? fcw[t] : fcb[0];
    if (t < 32){
        int gseq = blk*32 + t, n = gseq>>8, bb = gseq&255;
        float a = 0.f;
        for (int dd=0; dd<DD; dd++)
            a = fmaf(fcw[128+dd], infection[((size_t)bb*DD+dd)*DN+n], a);
        ((float*)(smb+INO))[t] = a;
    }

    // staging constants (t<288: x hi unit u = t = k8*32 + seq)
    int k81 = t >> 5, sq1 = t & 31;
    int gs1 = blk*32 + sq1;
    size_t cb1 = (size_t)(gs1 & 255)*DD*414 + (gs1>>8)*18 + k81;   // hsel=0
    int d1 = t*16;

    // output-tile constants
    const int mt0 = 2*w;
    const int jt  = mt0>>2, r3 = mt0&3;
    const int j8  = jt*2 + (lhi>>1);
    const int sub = (lhi&1)*8 + r3*2;
    const int j0  = jt*16 + lhi*4 + r3;

    __syncthreads();

    // prologue: stage x(0) hi into XB0
    if (t < 288){
        uint4 a0 = ntload4(zlin + cb1);
        *(uint4*)(smb + XB0O + d1) = a0;
    }
    __syncthreads();

    const float* bias0L = (const float*)(smb+B0O);
    const float* bias1L = (const float*)(smb+B1O);

    for (int step = 0; step < DD + DY; ++step){
        const int xb  = (step & 1) ? XB1O : XB0O;
        const int xbn = (step & 1) ? XB0O : XB1O;
        const bool do_stage = (step + 1 < DD);

        // ---------------- L0 MFMA (+ stage x(step+1)) ----------------
        {
            uint4 sv0; sv0.x=sv0.y=sv0.z=sv0.w=0u;
            if (do_stage && t < 288)
                sv0 = ntload4(zlin + (size_t)(step+1)*414 + cb1);

            f32x4 acc[2][2];
            #pragma unroll
            for (int mi=0;mi<2;mi++){
                int j = j0 + mi;
                f32x4 a;
                a[0]=bias0L[j]; a[1]=bias0L[128+j]; a[2]=bias0L[256+j]; a[3]=bias0L[384+j];
                acc[mi][0] = a; acc[mi][1] = a;
            }
            #pragma unroll 1
            for (int kt=0; kt<7; ++kt){
                const v8bf* wrow = w0p + (size_t)(kt*32 + mt0)*64 + l;
                v8bf A0 = wrow[0], A1 = wrow[64];
                int k8 = kt*4 + lhi;
                bool inx = (k8 <= 8);
                const char* hib = inx ? (smb + xb + k8*512) : (smb + H0O + (k8-9)*512);
                v8bf BH0 = *(const v8bf*)(hib + llo*16);
                v8bf BH1 = *(const v8bf*)(hib + 256 + llo*16);
                MFMA_(acc[0][0], A0, BH0);
                MFMA_(acc[1][0], A1, BH0);
                MFMA_(acc[0][1], A0, BH1);
                MFMA_(acc[1][1], A1, BH1);
            }
            if (do_stage && t < 288)
                *(uint4*)(smb + xbn + d1) = sv0;
            __syncthreads();   // B1: xb/H0 reads done

            // x2 accumulation of x(step) (hi only)
            if (step < DD && t < 288){
                const unsigned short* hp = (const unsigned short*)(smb + xb + t*16);
                float* xs = (float*)(smb + X2O);
                #pragma unroll
                for (int e=0;e<8;e++) xs[e*288+t] += bf2f(hp[e]);
            }

            // ACT L0 -> h0(step); c f32 in LDS slots
            #pragma unroll
            for (int nt=0;nt<2;nt++){
                unsigned short hh[2];
                #pragma unroll
                for (int mi=0;mi<2;mi++){
                    float* cslot = (float*)(smb + C0O) + (mi*2+nt)*1024 + t;
                    f32x4 a = acc[mi][nt];
                    float ii = fsig(a[0]), ff = fsig(a[1]), gg = ftanh(a[2]), oo = fsig(a[3]);
                    float c = ff*cslot[0] + ii*gg;
                    cslot[0] = c;
                    hh[mi] = f2bf(oo*ftanh(c));
                }
                unsigned ph = (unsigned)hh[0] | ((unsigned)hh[1]<<16);
                int bo = j8*512 + (nt*16+llo)*16 + sub;
                *(unsigned*)(smb + H0O + bo) = ph;
                *(unsigned*)(smb + U1O + bo) = ph;
            }
            __syncthreads();   // B2: h0 visible
        }

        // ---------------- L1 MFMA ----------------
        {
            f32x4 acc1[2][2];
            #pragma unroll
            for (int mi=0;mi<2;mi++){
                int j = j0 + mi;
                f32x4 a;
                a[0]=bias1L[j]; a[1]=bias1L[128+j]; a[2]=bias1L[256+j]; a[3]=bias1L[384+j];
                acc1[mi][0] = a; acc1[mi][1] = a;
            }
            #pragma unroll 1
            for (int kt=0; kt<8; ++kt){
                const v8bf* wrow = w1p + (size_t)(kt*32 + mt0)*64 + l;
                v8bf A0 = wrow[0], A1 = wrow[64];
                const char* hib = smb + U1O + (kt*4+lhi)*512;
                v8bf BH0 = *(const v8bf*)(hib + llo*16);
                v8bf BH1 = *(const v8bf*)(hib + 256 + llo*16);
                MFMA_(acc1[0][0], A0, BH0);
                MFMA_(acc1[1][0], A1, BH0);
                MFMA_(acc1[0][1], A0, BH1);
                MFMA_(acc1[1][1], A1, BH1);
            }
            __syncthreads();   // B3: U1 reads done

            // ACT L1 -> h1(step)
            #pragma unroll
            for (int nt=0;nt<2;nt++){
                unsigned short hh[2];
                #pragma unroll
                for (int mi=0;mi<2;mi++){
                    float* cslot = (float*)(smb + C1O) + (mi*2+nt)*1024 + t;
                    f32x4 a = acc1[mi][nt];
                    float ii = fsig(a[0]), ff = fsig(a[1]), gg = ftanh(a[2]), oo = fsig(a[3]);
                    float c = ff*cslot[0] + ii*gg;
                    cslot[0] = c;
                    hh[mi] = f2bf(oo*ftanh(c));
                }
                unsigned ph = (unsigned)hh[0] | ((unsigned)hh[1]<<16);
                int bo = (16+j8)*512 + (nt*16+llo)*16 + sub;
                *(unsigned*)(smb + U1O + bo) = ph;
            }
        }

        // ---- step 27: build decoder mean input (hi) into BOTH XB buffers
        if (step == DD-1){
            __syncthreads();
            if (t < 288){
                const float* xs = (const float*)(smb + X2O);
                __align__(16) unsigned short hb8[8];
                #pragma unroll
                for (int e=0;e<8;e++) hb8[e] = f2bf(xs[e*288+t] * (1.f/(float)DD));
                *(uint4*)(smb + XB0O + t*16) = *(const uint4*)hb8;
                *(uint4*)(smb + XB1O + t*16) = *(const uint4*)hb8;
            }
            __syncthreads();   // mean visible before step-28 L0 reads
        }

        // ---- decoder FC
        if (step >= DD){
            __syncthreads();   // h1 visible
            if (t < 256){
                int seq = t>>3, l8 = t&7;
                const unsigned short* uh = (const unsigned short*)(smb+U1O);
                const float* fw = (const float*)(smb+FCO);
                float a = 0.f;
                #pragma unroll
                for (int half=0; half<2; ++half){
                    int k8 = 16 + l8*2 + half;
                    int base = (k8*32 + seq)*8;
                    #pragma unroll
                    for (int e=0;e<8;e++){
                        int j = l8*16 + half*8 + e;
                        a = fmaf(fw[j], bf2f(uh[base+e]), a);
                    }
                }
                a += __shfl_down(a, 4, 8);
                a += __shfl_down(a, 2, 8);
                a += __shfl_down(a, 1, 8);
                if (l8 == 0){
                    int gseq = blk*32 + seq, n = gseq>>8, bb = gseq&255;
                    float yv = fmaxf(a + ((const float*)(smb+INO))[seq] + fw[128], 0.f);
                    __builtin_nontemporal_store(yv, &outy[((size_t)bb*DY + (step-DD))*DN + n]);
                }
            }
        }
        // no closing barrier for encoder steps (R7-proven scheme)
    }
}

// ---------------------------------------------------------------------------
extern "C" void kernel_launch(void* const* d_in, const int* in_sizes, int n_in,
                              void* d_out, int out_size, void* d_ws, size_t ws_size,
                              hipStream_t stream)
{
    const float* x         = (const float*)d_in[0];
    const float* adj_real  = (const float*)d_in[1];
    const float* infection = (const float*)d_in[2];
    const int*   day_order = (const int*)  d_in[3];
    const float* gl_w1     = (const float*)d_in[4];
    const float* gl_b1     = (const float*)d_in[5];
    const float* gl_w2     = (const float*)d_in[6];
    const float* gl_b2     = (const float*)d_in[7];
    const float* glp       = (const float*)d_in[8];
    const float* gcn_w     = (const float*)d_in[9];
    const float* vvec      = (const float*)d_in[10];
    const float* wih0      = (const float*)d_in[11];
    const float* whh0      = (const float*)d_in[12];
    const float* b0        = (const float*)d_in[13];
    const float* wih1      = (const float*)d_in[14];
    const float* whh1      = (const float*)d_in[15];
    const float* b1        = (const float*)d_in[16];
    const float* fcw       = (const float*)d_in[17];
    const float* fcb       = (const float*)d_in[18];

    uint8_t* wsb = (uint8_t*)d_ws;
    uint4*          zlin = (uint4*)(wsb);
    unsigned short* wb0  = (unsigned short*)(wsb + WB0_OFF);
    unsigned short* wb1  = (unsigned short*)(wsb + WB1_OFF);
    unsigned short* wpk  = (unsigned short*)(wsb + WPK_OFF);
    unsigned short* gpk  = (unsigned short*)(wsb + GPK_OFF);
    float* out_adj = (float*)d_out;
    float* out_y   = out_adj + ADJSZ;

    kernPrep<<<dim3(1248), dim3(256), 0, stream>>>(wih0, whh0, wih1, whh1,
                                                   gl_w1, gl_w2, gcn_w,
                                                   wb0, wb1, wpk, gpk);
    kernA<<<dim3(DB*DD), dim3(256), 0, stream>>>(x, adj_real, infection, day_order,
                                                 gl_b1, gl_b2, glp, vvec,
                                                 (const v8bf*)wpk, (const v8bf*)gpk,
                                                 out_adj, zlin);
    kernB<<<dim3(GBLK), dim3(1024), 0, stream>>>(zlin, (const v8bf*)wb0,
                                                 (const v8bf*)wb1, b0, b1, infection,
                                                 fcw, fcb, out_y);
}

// Round 14
// 438.093 us; speedup vs baseline: 1.5948x; 1.1319x over previous
//
#include <hip/hip_runtime.h>
#include <hip/hip_bf16.h>
#include <stdint.h>

// ---------------------------------------------------------------------------
// B=256 D=28 N=23 F=128 O=64 H=128 Y=7.  NBSEQ=5888 = 184 blocks x 32 seqs.
// R14:
//  kernB: kt loops unroll 1 -> 2 (double the in-flight weight loads; peak regs
//         ~52+12 = 64 = cap; falsified by WRITE_SIZE if it spills).
//  kernA: A3 (s12) MFMA-ized, 3-term hi/lo product (adj accuracy preserved).
//         A7 moved before A2 so xhl dies at A2-MFMA end; n1lo/n2lo alias the
//         xhl region -> LDS 51.9KB, still 3 blocks/CU.  deg hoisted off the
//         barrier-critical path.  n-buffers stride 136 (16B-aligned frags).
// ---------------------------------------------------------------------------

#define DB 256
#define DD 28
#define DN 23
#define DF 128
#define DO 64
#define DH 128
#define DY 7
#define NBSEQ (DN*DB)
#define ADJSZ (DB*DD*DN*DN)
#define GBLK 184

// workspace byte offsets
#define WB0_OFF   47480832u            // zlin = 7168*414*16
#define WB1_OFF   47710208u
#define WPK_OFF   47972352u
#define GPK_OFF   48103424u

using v8bf  = __attribute__((ext_vector_type(8))) __bf16;
using f32x4 = __attribute__((ext_vector_type(4))) float;
using u32x4 = __attribute__((ext_vector_type(4))) unsigned int;

__device__ __forceinline__ float fsig(float x)  { return 1.f/(1.f+__expf(-x)); }
__device__ __forceinline__ float ftanh(float x) { return 1.f - 2.f/(__expf(2.f*x)+1.f); }

__device__ __forceinline__ unsigned short f2bf(float f){
    unsigned u = __builtin_bit_cast(unsigned, f);
    return (unsigned short)((u + 0x7FFFu + ((u>>16)&1u)) >> 16);
}
__device__ __forceinline__ float bf2f(unsigned short b){
    return __builtin_bit_cast(float, (unsigned)b << 16);
}
__device__ __forceinline__ uint4 ntload4(const uint4* p){
    u32x4 v = __builtin_nontemporal_load((const u32x4*)p);
    return *(uint4*)&v;
}

#define MFMA_(acc_, A_, B_) acc_ = __builtin_amdgcn_mfma_f32_16x16x32_bf16(A_, B_, acc_, 0, 0, 0)

// ---------------------------------------------------------------------------
// Prep (unchanged R9)
// ---------------------------------------------------------------------------
__global__ __launch_bounds__(256) void kernPrep(
    const float* __restrict__ wih0, const float* __restrict__ whh0,
    const float* __restrict__ wih1, const float* __restrict__ whh1,
    const float* __restrict__ glw1, const float* __restrict__ glw2,
    const float* __restrict__ gcn_w,
    unsigned short* __restrict__ wb0, unsigned short* __restrict__ wb1,
    unsigned short* __restrict__ wpk, unsigned short* __restrict__ gpk)
{
    int idx = blockIdx.x*256 + threadIdx.x;
    if (idx < 114688){
        int e = idx&7, l = (idx>>3)&63, mt = (idx>>9)&31, kt = idx>>14;
        int rit = l&15, lj = rit>>2, g = rit&3;
        int r = g*128 + (mt>>2)*16 + lj*4 + (mt&3);
        int k = kt*32 + (l>>4)*8 + e;
        float v = 0.f;
        if (k < 65)                  v = wih0[r*65 + k];
        else if (k >= 72 && k < 200) v = whh0[r*128 + (k-72)];
        wb0[idx] = f2bf(v);
        return;
    }
    idx -= 114688;
    if (idx < 131072){
        int e = idx&7, l = (idx>>3)&63, mt = (idx>>9)&31, kt = idx>>14;
        int rit = l&15, lj = rit>>2, g = rit&3;
        int r = g*128 + (mt>>2)*16 + lj*4 + (mt&3);
        int k = kt*32 + (l>>4)*8 + e;
        float v = (k < 128) ? wih1[r*128 + k] : whh1[r*128 + (k-128)];
        wb1[idx] = f2bf(v);
        return;
    }
    idx -= 131072;
    if (idx < 65536){
        int e = idx&7, l = (idx>>3)&63, hsel = (idx>>9)&1, kt = (idx>>10)&3,
            nt = (idx>>12)&7, mat = (idx>>15)&1;
        int fo = nt*16 + (l&15);
        int k  = kt*32 + (l>>4)*8 + e;
        float v = (mat ? glw2 : glw1)[fo*128 + k];
        unsigned short hb = f2bf(v);
        wpk[idx] = hsel ? f2bf(v - bf2f(hb)) : hb;
        return;
    }
    idx -= 65536;
    if (idx < 8192){
        int e = idx&7, l = (idx>>3)&63, kt = (idx>>9)&3, nt = (idx>>11)&3;
        int o = nt*16 + (l&15);
        int k = kt*32 + (l>>4)*8 + e;
        gpk[idx] = f2bf(gcn_w[k*64 + o]);
    }
}

// ---------------------------------------------------------------------------
// Kernel A: per-(b,d) graph stage.  grid = 7168, block = 256 (4 waves).
// Order: stage -> A7(MFMA, xhl) + deg -> A2(MFMA, xhl) -> [xhl dead] ->
// epilogue(n1/n2 hi+lo; lo aliases xhl) -> A3(MFMA s12, 3-term) -> A4 ->
// A5 -> A6 -> A8 -> pack.  LDS 51.9KB -> 3 blocks/CU.
// ---------------------------------------------------------------------------
__global__ __launch_bounds__(256) void kernA(
    const float* __restrict__ x, const float* __restrict__ adj_real,
    const float* __restrict__ infection, const int* __restrict__ day_order,
    const float* __restrict__ b1, const float* __restrict__ b2,
    const float* __restrict__ glp, const float* __restrict__ vvec,
    const v8bf* __restrict__ wpk, const v8bf* __restrict__ gpk,
    float* __restrict__ out_adj, uint4* __restrict__ zlin4)
{
    const int bd = blockIdx.x;
    const int b  = bd / DD;
    const int t  = threadIdx.x;
    const int w  = t>>6, l = t&63;

    __shared__ float sm[4140];
    const int S12=0, ADJ=552, XW=1104, DEG=2576, DINV=2599, FACT=2622,
              INFS=2645, GC=2668;
    __shared__ __align__(16) unsigned short xhl[2][32][140];
    __shared__ __align__(16) unsigned short n1b[32*136];
    __shared__ __align__(16) unsigned short n2b[32*136];
    unsigned short* n1l = &xhl[0][0][0];   // alias: xhl dead after A2 MFMA
    unsigned short* n2l = n1l + 32*136;

    // ---- stage: x hi/lo, pads, FACT/INFS, zero n1b/n2b pad rows
    const float* xg = x + (size_t)bd*(DN*DF);
    for (int p=t; p<DN*DF; p+=256){
        int n = p>>7, k = p&127;
        float v = xg[p];
        unsigned short hb = f2bf(v);
        xhl[0][n][k] = hb;
        xhl[1][n][k] = f2bf(v - bf2f(hb));
    }
    for (int p=t; p<9*DF; p+=256){
        int n = DN + (p>>7), k = p&127;
        xhl[0][n][k] = 0; xhl[1][n][k] = 0;
    }
    {
        uint4 z; z.x=z.y=z.z=z.w=0u;
        for (int i=t; i<306; i+=256){
            int bsel = (i >= 153), off = bsel ? i-153 : i;
            *(uint4*)((char*)(bsel ? n2b : n1b) + 6256 + off*16) = z;   // rows 23..31
        }
    }
    if (t < DN){
        float vv = vvec[t];
        sm[FACT+t] = __expf(vv*vv*(float)day_order[b]);
        sm[INFS+t] = infection[(size_t)bd*DN + t];
    }
    __syncthreads();

    // ---- A7 (MFMA): xw = x @ gcn_w   (xhl reader; XW unread until A8)
    {
        f32x4 acc2[2];
        { f32x4 z; z[0]=z[1]=z[2]=z[3]=0.f; acc2[0]=z; acc2[1]=z; }
        #pragma unroll
        for (int kt=0;kt<4;kt++){
            v8bf ah[2], al[2];
            #pragma unroll
            for (int mt=0;mt<2;mt++){
                int m = mt*16 + (l&15);
                int ko = (l>>4)*8 + kt*32;
                ah[mt] = *(const v8bf*)&xhl[0][m][ko];
                al[mt] = *(const v8bf*)&xhl[1][m][ko];
            }
            v8bf gh = gpk[(size_t)(w*4+kt)*64 + l];
            MFMA_(acc2[0], ah[0], gh);
            MFMA_(acc2[1], ah[1], gh);
            MFMA_(acc2[0], al[0], gh);
            MFMA_(acc2[1], al[1], gh);
        }
        int o = w*16 + (l&15);
        #pragma unroll
        for (int mt=0;mt<2;mt++){
            #pragma unroll
            for (int r=0;r<4;r++){
                int n = mt*16 + (l>>4)*4 + r;
                if (n < DN) sm[XW + n*64 + o] = acc2[mt][r];
            }
        }
    }

    // ---- deg (t<23): rowsum of adj_real  (off the barrier-critical path)
    if (t < DN){
        const float* ar = adj_real + (size_t)bd*(DN*DN) + t*DN;
        float s = 0.f;
        for (int m=0;m<DN;m++) s += ar[m];
        sm[DEG+t] = s;
    }

    // ---- A2 (MFMA): n1/n2 = tanh(x @ W^T + b)
    {
        const int mat = w>>1;
        const int ntb = (w&1)*4;
        const float* bsrc = mat ? b2 : b1;
        float bias[4];
        #pragma unroll
        for (int q=0;q<4;q++) bias[q] = bsrc[(ntb+q)*16 + (l&15)];
        f32x4 acc[2][4];
        #pragma unroll
        for (int mt=0;mt<2;mt++)
            #pragma unroll
            for (int q=0;q<4;q++){ f32x4 z; z[0]=z[1]=z[2]=z[3]=0.f; acc[mt][q]=z; }
        #pragma unroll
        for (int kt=0;kt<4;kt++){
            v8bf ah[2], al[2];
            #pragma unroll
            for (int mt=0;mt<2;mt++){
                int m = mt*16 + (l&15);
                int ko = (l>>4)*8 + kt*32;
                ah[mt] = *(const v8bf*)&xhl[0][m][ko];
                al[mt] = *(const v8bf*)&xhl[1][m][ko];
            }
            #pragma unroll
            for (int q=0;q<4;q++){
                const v8bf* wb = wpk + ((size_t)(((mat*8+(ntb+q))*4+kt)*2)*64 + l);
                v8bf wh = wb[0], wl = wb[64];
                MFMA_(acc[0][q], ah[0], wh);
                MFMA_(acc[1][q], ah[1], wh);
                MFMA_(acc[0][q], al[0], wh);
                MFMA_(acc[1][q], al[1], wh);
                MFMA_(acc[0][q], ah[0], wl);
                MFMA_(acc[1][q], ah[1], wl);
            }
        }
        __syncthreads();   // all xhl reads (A7+A2) done; alias region reusable

        // epilogue: n1/n2 hi+lo (lo in xhl alias); zero lo pad rows
        unsigned short* dsth = mat ? n2b : n1b;
        unsigned short* dstl = mat ? n2l : n1l;
        #pragma unroll
        for (int mt=0;mt<2;mt++){
            #pragma unroll
            for (int q=0;q<4;q++){
                int fo = (ntb+q)*16 + (l&15);
                #pragma unroll
                for (int r=0;r<4;r++){
                    int n = mt*16 + (l>>4)*4 + r;
                    if (n < DN){
                        float nv = ftanh(acc[mt][q][r] + bias[q]);
                        unsigned short hb = f2bf(nv);
                        dsth[n*136 + fo] = hb;
                        dstl[n*136 + fo] = f2bf(nv - bf2f(hb));
                    }
                }
            }
        }
        {
            uint4 z; z.x=z.y=z.z=z.w=0u;
            for (int i=t; i<306; i+=256){
                int bsel = (i >= 153), off = bsel ? i-153 : i;
                *(uint4*)((char*)(bsel ? n2l : n1l) + 6256 + off*16) = z;
            }
        }
    }
    __syncthreads();

    // ---- A3 (MFMA): s12 = n1 @ n2^T, 3-term hi/lo.  wave w -> (mt,nt).
    {
        const int mt = w>>1, nt = w&1;
        f32x4 a3; a3[0]=a3[1]=a3[2]=a3[3]=0.f;
        #pragma unroll
        for (int kt=0;kt<4;kt++){
            int ar = (mt*16+(l&15))*136 + kt*32 + (l>>4)*8;
            int br = (nt*16+(l&15))*136 + kt*32 + (l>>4)*8;
            v8bf ah  = *(const v8bf*)&n1b[ar];
            v8bf alo = *(const v8bf*)&n1l[ar];
            v8bf bh  = *(const v8bf*)&n2b[br];
            v8bf blo = *(const v8bf*)&n2l[br];
            MFMA_(a3, ah,  bh);
            MFMA_(a3, alo, bh);
            MFMA_(a3, ah,  blo);
        }
        #pragma unroll
        for (int r=0;r<4;r++){
            int i = mt*16 + (l>>4)*4 + r;
            int j = nt*16 + (l&15);
            if (i < DN && j < DN) sm[S12 + i*24 + j] = a3[r];
        }
    }
    __syncthreads();

    // ---- A4: adj
    for (int p=t; p<DN*DN; p+=256){
        int i=p/DN, j=p-i*DN;
        float al  = fmaxf(ftanh(sm[S12+i*24+j]-sm[S12+j*24+i]), 0.f);
        float md  = fsig(glp[i*DN+j]*sm[DEG+i]*sm[DEG+j]);
        float arv = adj_real[(size_t)bd*(DN*DN) + p];
        float adjv = al + md*arv;
        __builtin_nontemporal_store(adjv, &out_adj[(size_t)bd*(DN*DN) + p]);
        sm[ADJ + i*24 + j] = adjv + (i==j ? 1.f : 0.f);
    }
    __syncthreads();

    if (t<DN){
        float rs=0.f;
        for (int jj=0;jj<DN;jj++) rs += sm[ADJ+t*24+jj];
        sm[DINV+t] = rsqrtf(rs);
    }
    __syncthreads();

    // ---- A6: dad in place
    for (int p=t;p<DN*DN;p+=256){
        int i=p/DN, j=p-i*DN;
        sm[ADJ+i*24+j] *= sm[DINV+i]*sm[DINV+j];
    }
    __syncthreads();

    // ---- A8: gcn = relu(dad @ xw) * factor -> GC
    for (int p=t;p<DN*64;p+=256){
        int n=p>>6, o=p&63;
        float a=0.f;
        #pragma unroll
        for (int m=0;m<DN;m++) a = fmaf(sm[ADJ+n*24+m], sm[XW+m*64+o], a);
        sm[GC + p] = fmaxf(a,0.f)*sm[FACT+n];
    }
    __syncthreads();

    // ---- pack -> zlin[bd][414]
    for (int p=t; p<DN*18; p+=256){
        int n = p/18, r = p - n*18, hsel = r/9, k8 = r - hsel*9;
        __align__(16) unsigned short ob[8];
        #pragma unroll
        for (int e=0;e<8;e++){
            int k = k8*8+e;
            float v = (k<64) ? sm[GC + n*64 + k] : ((k==64) ? sm[INFS+n] : 0.f);
            unsigned short hb = f2bf(v);
            ob[e] = hsel ? f2bf(v - bf2f(hb)) : hb;
        }
        zlin4[(size_t)bd*414 + p] = *(const uint4*)ob;
    }
}

// ---------------------------------------------------------------------------
// Kernel B: MFMA LSTM.  grid=184, block=1024 (16 waves), 32 seqs/block.
// Wave w: M-tiles 2w, 2w+1.  acc[2][2]=16 VGPR; c-states f32 in LDS slots;
// HI-ONLY bf16 operands (R13).  kt loops at unroll 2 (R14: 2-deep prefetch).
// ---------------------------------------------------------------------------
#define XB0O 0
#define XB1O 9216
#define H0O  18432
#define U1O  37888
#define X2O  70656
#define B0O  79872
#define B1O  81920
#define FCO  83968
#define INO  84488
#define C0O  84624
#define C1O  101008
// end 117392

__global__ __launch_bounds__(1024, 2) void kernB(
    const uint4* __restrict__ zlin, const v8bf* __restrict__ w0p, const v8bf* __restrict__ w1p,
    const float* __restrict__ b0g, const float* __restrict__ b1g,
    const float* __restrict__ infection, const float* __restrict__ fcw,
    const float* __restrict__ fcb, float* __restrict__ outy)
{
    const int t = threadIdx.x, blk = blockIdx.x;
    const int w = t>>6, l = t&63;
    const int lhi = l>>4, llo = l&15;
    __shared__ __align__(16) unsigned char smraw[117392];
    char* smb = (char*)smraw;

    {
        uint4 z; z.x=z.y=z.z=z.w=0u;
        for (int i = t; i < (79872-18432)/16; i += 1024) ((uint4*)(smb+18432))[i] = z;
        for (int i = t; i < (117392-84624)/16; i += 1024) ((uint4*)(smb+84624))[i] = z;
    }
    if (t < 512){
        ((float*)(smb+B0O))[t] = b0g[t];
        ((float*)(smb+B1O))[t] = b1g[t];
    }
    if (t < 129) ((float*)(smb+FCO))[t] = (t<128) ? fcw[t] : fcb[0];
    if (t < 32){
        int gseq = blk*32 + t, n = gseq>>8, bb = gseq&255;
        float a = 0.f;
        for (int dd=0; dd<DD; dd++)
            a = fmaf(fcw[128+dd], infection[((size_t)bb*DD+dd)*DN+n], a);
        ((float*)(smb+INO))[t] = a;
    }

    int k81 = t >> 5, sq1 = t & 31;
    int gs1 = blk*32 + sq1;
    size_t cb1 = (size_t)(gs1 & 255)*DD*414 + (gs1>>8)*18 + k81;   // hsel=0
    int d1 = t*16;

    const int mt0 = 2*w;
    const int jt  = mt0>>2, r3 = mt0&3;
    const int j8  = jt*2 + (lhi>>1);
    const int sub = (lhi&1)*8 + r3*2;
    const int j0  = jt*16 + lhi*4 + r3;

    __syncthreads();

    if (t < 288){
        uint4 a0 = ntload4(zlin + cb1);
        *(uint4*)(smb + XB0O + d1) = a0;
    }
    __syncthreads();

    const float* bias0L = (const float*)(smb+B0O);
    const float* bias1L = (const float*)(smb+B1O);

    for (int step = 0; step < DD + DY; ++step){
        const int xb  = (step & 1) ? XB1O : XB0O;
        const int xbn = (step & 1) ? XB0O : XB1O;
        const bool do_stage = (step + 1 < DD);

        // ---------------- L0 MFMA (+ stage x(step+1)) ----------------
        {
            uint4 sv0; sv0.x=sv0.y=sv0.z=sv0.w=0u;
            if (do_stage && t < 288)
                sv0 = ntload4(zlin + (size_t)(step+1)*414 + cb1);

            f32x4 acc[2][2];
            #pragma unroll
            for (int mi=0;mi<2;mi++){
                int j = j0 + mi;
                f32x4 a;
                a[0]=bias0L[j]; a[1]=bias0L[128+j]; a[2]=bias0L[256+j]; a[3]=bias0L[384+j];
                acc[mi][0] = a; acc[mi][1] = a;
            }
            #pragma unroll 2
            for (int kt=0; kt<7; ++kt){
                const v8bf* wrow = w0p + (size_t)(kt*32 + mt0)*64 + l;
                v8bf A0 = wrow[0], A1 = wrow[64];
                int k8 = kt*4 + lhi;
                bool inx = (k8 <= 8);
                const char* hib = inx ? (smb + xb + k8*512) : (smb + H0O + (k8-9)*512);
                v8bf BH0 = *(const v8bf*)(hib + llo*16);
                v8bf BH1 = *(const v8bf*)(hib + 256 + llo*16);
                MFMA_(acc[0][0], A0, BH0);
                MFMA_(acc[1][0], A1, BH0);
                MFMA_(acc[0][1], A0, BH1);
                MFMA_(acc[1][1], A1, BH1);
            }
            if (do_stage && t < 288)
                *(uint4*)(smb + xbn + d1) = sv0;
            __syncthreads();   // B1: xb/H0 reads done

            if (step < DD && t < 288){
                const unsigned short* hp = (const unsigned short*)(smb + xb + t*16);
                float* xs = (float*)(smb + X2O);
                #pragma unroll
                for (int e=0;e<8;e++) xs[e*288+t] += bf2f(hp[e]);
            }

            #pragma unroll
            for (int nt=0;nt<2;nt++){
                unsigned short hh[2];
                #pragma unroll
                for (int mi=0;mi<2;mi++){
                    float* cslot = (float*)(smb + C0O) + (mi*2+nt)*1024 + t;
                    f32x4 a = acc[mi][nt];
                    float ii = fsig(a[0]), ff = fsig(a[1]), gg = ftanh(a[2]), oo = fsig(a[3]);
                    float c = ff*cslot[0] + ii*gg;
                    cslot[0] = c;
                    hh[mi] = f2bf(oo*ftanh(c));
                }
                unsigned ph = (unsigned)hh[0] | ((unsigned)hh[1]<<16);
                int bo = j8*512 + (nt*16+llo)*16 + sub;
                *(unsigned*)(smb + H0O + bo) = ph;
                *(unsigned*)(smb + U1O + bo) = ph;
            }
            __syncthreads();   // B2: h0 visible
        }

        // ---------------- L1 MFMA ----------------
        {
            f32x4 acc1[2][2];
            #pragma unroll
            for (int mi=0;mi<2;mi++){
                int j = j0 + mi;
                f32x4 a;
                a[0]=bias1L[j]; a[1]=bias1L[128+j]; a[2]=bias1L[256+j]; a[3]=bias1L[384+j];
                acc1[mi][0] = a; acc1[mi][1] = a;
            }
            #pragma unroll 2
            for (int kt=0; kt<8; ++kt){
                const v8bf* wrow = w1p + (size_t)(kt*32 + mt0)*64 + l;
                v8bf A0 = wrow[0], A1 = wrow[64];
                const char* hib = smb + U1O + (kt*4+lhi)*512;
                v8bf BH0 = *(const v8bf*)(hib + llo*16);
                v8bf BH1 = *(const v8bf*)(hib + 256 + llo*16);
                MFMA_(acc1[0][0], A0, BH0);
                MFMA_(acc1[1][0], A1, BH0);
                MFMA_(acc1[0][1], A0, BH1);
                MFMA_(acc1[1][1], A1, BH1);
            }
            __syncthreads();   // B3: U1 reads done

            #pragma unroll
            for (int nt=0;nt<2;nt++){
                unsigned short hh[2];
                #pragma unroll
                for (int mi=0;mi<2;mi++){
                    float* cslot = (float*)(smb + C1O) + (mi*2+nt)*1024 + t;
                    f32x4 a = acc1[mi][nt];
                    float ii = fsig(a[0]), ff = fsig(a[1]), gg = ftanh(a[2]), oo = fsig(a[3]);
                    float c = ff*cslot[0] + ii*gg;
                    cslot[0] = c;
                    hh[mi] = f2bf(oo*ftanh(c));
                }
                unsigned ph = (unsigned)hh[0] | ((unsigned)hh[1]<<16);
                int bo = (16+j8)*512 + (nt*16+llo)*16 + sub;
                *(unsigned*)(smb + U1O + bo) = ph;
            }
        }

        if (step == DD-1){
            __syncthreads();
            if (t < 288){
                const float* xs = (const float*)(smb + X2O);
                __align__(16) unsigned short hb8[8];
                #pragma unroll
                for (int e=0;e<8;e++) hb8[e] = f2bf(xs[e*288+t] * (1.f/(float)DD));
                *(uint4*)(smb + XB0O + t*16) = *(const uint4*)hb8;
                *(uint4*)(smb + XB1O + t*16) = *(const uint4*)hb8;
            }
            __syncthreads();
        }

        if (step >= DD){
            __syncthreads();
            if (t < 256){
                int seq = t>>3, l8 = t&7;
                const unsigned short* uh = (const unsigned short*)(smb+U1O);
                const float* fw = (const float*)(smb+FCO);
                float a = 0.f;
                #pragma unroll
                for (int half=0; half<2; ++half){
                    int k8 = 16 + l8*2 + half;
                    int base = (k8*32 + seq)*8;
                    #pragma unroll
                    for (int e=0;e<8;e++){
                        int j = l8*16 + half*8 + e;
                        a = fmaf(fw[j], bf2f(uh[base+e]), a);
                    }
                }
                a += __shfl_down(a, 4, 8);
                a += __shfl_down(a, 2, 8);
                a += __shfl_down(a, 1, 8);
                if (l8 == 0){
                    int gseq = blk*32 + seq, n = gseq>>8, bb = gseq&255;
                    float yv = fmaxf(a + ((const float*)(smb+INO))[seq] + fw[128], 0.f);
                    __builtin_nontemporal_store(yv, &outy[((size_t)bb*DY + (step-DD))*DN + n]);
                }
            }
        }
    }
}

// ---------------------------------------------------------------------------
extern "C" void kernel_launch(void* const* d_in, const int* in_sizes, int n_in,
                              void* d_out, int out_size, void* d_ws, size_t ws_size,
                              hipStream_t stream)
{
    const float* x         = (const float*)d_in[0];
    const float* adj_real  = (const float*)d_in[1];
    const float* infection = (const float*)d_in[2];
    const int*   day_order = (const int*)  d_in[3];
    const float* gl_w1     = (const float*)d_in[4];
    const float* gl_b1     = (const float*)d_in[5];
    const float* gl_w2     = (const float*)d_in[6];
    const float* gl_b2     = (const float*)d_in[7];
    const float* glp       = (const float*)d_in[8];
    const float* gcn_w     = (const float*)d_in[9];
    const float* vvec      = (const float*)d_in[10];
    const float* wih0      = (const float*)d_in[11];
    const float* whh0      = (const float*)d_in[12];
    const float* b0        = (const float*)d_in[13];
    const float* wih1      = (const float*)d_in[14];
    const float* whh1      = (const float*)d_in[15];
    const float* b1        = (const float*)d_in[16];
    const float* fcw       = (const float*)d_in[17];
    const float* fcb       = (const float*)d_in[18];

    uint8_t* wsb = (uint8_t*)d_ws;
    uint4*          zlin = (uint4*)(wsb);
    unsigned short* wb0  = (unsigned short*)(wsb + WB0_OFF);
    unsigned short* wb1  = (unsigned short*)(wsb + WB1_OFF);
    unsigned short* wpk  = (unsigned short*)(wsb + WPK_OFF);
    unsigned short* gpk  = (unsigned short*)(wsb + GPK_OFF);
    float* out_adj = (float*)d_out;
    float* out_y   = out_adj + ADJSZ;

    kernPrep<<<dim3(1248), dim3(256), 0, stream>>>(wih0, whh0, wih1, whh1,
                                                   gl_w1, gl_w2, gcn_w,
                                                   wb0, wb1, wpk, gpk);
    kernA<<<dim3(DB*DD), dim3(256), 0, stream>>>(x, adj_real, infection, day_order,
                                                 gl_b1, gl_b2, glp, vvec,
                                                 (const v8bf*)wpk, (const v8bf*)gpk,
                                                 out_adj, zlin);
    kernB<<<dim3(GBLK), dim3(1024), 0, stream>>>(zlin, (const v8bf*)wb0,
                                                 (const v8bf*)wb1, b0, b1, infection,
                                                 fcw, fcb, out_y);
}

// Round 15
// 432.471 us; speedup vs baseline: 1.6156x; 1.0130x over previous
//
#include <hip/hip_runtime.h>
#include <hip/hip_bf16.h>
#include <stdint.h>

// ---------------------------------------------------------------------------
// B=256 D=28 N=23 F=128 O=64 H=128 Y=7.  NBSEQ=5888 = 184 blocks x 32 seqs.
// R15: kernB -> ONE barrier per encoder step.  All cross-wave LDS surfaces
//      double-buffered by step parity (H0, U1-h0, U1-h1; x already was).
//      Dependency audit: every cross-wave write->read separated by >=1 B2;
//      overwrite hazards gated by the barrier chain (slow reader pre-B2(s+k)
//      blocks fast writer post-B2(s+k)).  LDS 117->108KB.
//      kernA/kernPrep unchanged (R14).
// ---------------------------------------------------------------------------

#define DB 256
#define DD 28
#define DN 23
#define DF 128
#define DO 64
#define DH 128
#define DY 7
#define NBSEQ (DN*DB)
#define ADJSZ (DB*DD*DN*DN)
#define GBLK 184

// workspace byte offsets
#define WB0_OFF   47480832u            // zlin = 7168*414*16
#define WB1_OFF   47710208u
#define WPK_OFF   47972352u
#define GPK_OFF   48103424u

using v8bf  = __attribute__((ext_vector_type(8))) __bf16;
using f32x4 = __attribute__((ext_vector_type(4))) float;
using u32x4 = __attribute__((ext_vector_type(4))) unsigned int;

__device__ __forceinline__ float fsig(float x)  { return 1.f/(1.f+__expf(-x)); }
__device__ __forceinline__ float ftanh(float x) { return 1.f - 2.f/(__expf(2.f*x)+1.f); }

__device__ __forceinline__ unsigned short f2bf(float f){
    unsigned u = __builtin_bit_cast(unsigned, f);
    return (unsigned short)((u + 0x7FFFu + ((u>>16)&1u)) >> 16);
}
__device__ __forceinline__ float bf2f(unsigned short b){
    return __builtin_bit_cast(float, (unsigned)b << 16);
}
__device__ __forceinline__ uint4 ntload4(const uint4* p){
    u32x4 v = __builtin_nontemporal_load((const u32x4*)p);
    return *(uint4*)&v;
}

#define MFMA_(acc_, A_, B_) acc_ = __builtin_amdgcn_mfma_f32_16x16x32_bf16(A_, B_, acc_, 0, 0, 0)

// ---------------------------------------------------------------------------
// Prep (unchanged)
// ---------------------------------------------------------------------------
__global__ __launch_bounds__(256) void kernPrep(
    const float* __restrict__ wih0, const float* __restrict__ whh0,
    const float* __restrict__ wih1, const float* __restrict__ whh1,
    const float* __restrict__ glw1, const float* __restrict__ glw2,
    const float* __restrict__ gcn_w,
    unsigned short* __restrict__ wb0, unsigned short* __restrict__ wb1,
    unsigned short* __restrict__ wpk, unsigned short* __restrict__ gpk)
{
    int idx = blockIdx.x*256 + threadIdx.x;
    if (idx < 114688){
        int e = idx&7, l = (idx>>3)&63, mt = (idx>>9)&31, kt = idx>>14;
        int rit = l&15, lj = rit>>2, g = rit&3;
        int r = g*128 + (mt>>2)*16 + lj*4 + (mt&3);
        int k = kt*32 + (l>>4)*8 + e;
        float v = 0.f;
        if (k < 65)                  v = wih0[r*65 + k];
        else if (k >= 72 && k < 200) v = whh0[r*128 + (k-72)];
        wb0[idx] = f2bf(v);
        return;
    }
    idx -= 114688;
    if (idx < 131072){
        int e = idx&7, l = (idx>>3)&63, mt = (idx>>9)&31, kt = idx>>14;
        int rit = l&15, lj = rit>>2, g = rit&3;
        int r = g*128 + (mt>>2)*16 + lj*4 + (mt&3);
        int k = kt*32 + (l>>4)*8 + e;
        float v = (k < 128) ? wih1[r*128 + k] : whh1[r*128 + (k-128)];
        wb1[idx] = f2bf(v);
        return;
    }
    idx -= 131072;
    if (idx < 65536){
        int e = idx&7, l = (idx>>3)&63, hsel = (idx>>9)&1, kt = (idx>>10)&3,
            nt = (idx>>12)&7, mat = (idx>>15)&1;
        int fo = nt*16 + (l&15);
        int k  = kt*32 + (l>>4)*8 + e;
        float v = (mat ? glw2 : glw1)[fo*128 + k];
        unsigned short hb = f2bf(v);
        wpk[idx] = hsel ? f2bf(v - bf2f(hb)) : hb;
        return;
    }
    idx -= 65536;
    if (idx < 8192){
        int e = idx&7, l = (idx>>3)&63, kt = (idx>>9)&3, nt = (idx>>11)&3;
        int o = nt*16 + (l&15);
        int k = kt*32 + (l>>4)*8 + e;
        gpk[idx] = f2bf(gcn_w[k*64 + o]);
    }
}

// ---------------------------------------------------------------------------
// Kernel A (unchanged R14): per-(b,d) graph stage -> adj + zlin[bd][414].
// ---------------------------------------------------------------------------
__global__ __launch_bounds__(256) void kernA(
    const float* __restrict__ x, const float* __restrict__ adj_real,
    const float* __restrict__ infection, const int* __restrict__ day_order,
    const float* __restrict__ b1, const float* __restrict__ b2,
    const float* __restrict__ glp, const float* __restrict__ vvec,
    const v8bf* __restrict__ wpk, const v8bf* __restrict__ gpk,
    float* __restrict__ out_adj, uint4* __restrict__ zlin4)
{
    const int bd = blockIdx.x;
    const int b  = bd / DD;
    const int t  = threadIdx.x;
    const int w  = t>>6, l = t&63;

    __shared__ float sm[4140];
    const int S12=0, ADJ=552, XW=1104, DEG=2576, DINV=2599, FACT=2622,
              INFS=2645, GC=2668;
    __shared__ __align__(16) unsigned short xhl[2][32][140];
    __shared__ __align__(16) unsigned short n1b[32*136];
    __shared__ __align__(16) unsigned short n2b[32*136];
    unsigned short* n1l = &xhl[0][0][0];
    unsigned short* n2l = n1l + 32*136;

    const float* xg = x + (size_t)bd*(DN*DF);
    for (int p=t; p<DN*DF; p+=256){
        int n = p>>7, k = p&127;
        float v = xg[p];
        unsigned short hb = f2bf(v);
        xhl[0][n][k] = hb;
        xhl[1][n][k] = f2bf(v - bf2f(hb));
    }
    for (int p=t; p<9*DF; p+=256){
        int n = DN + (p>>7), k = p&127;
        xhl[0][n][k] = 0; xhl[1][n][k] = 0;
    }
    {
        uint4 z; z.x=z.y=z.z=z.w=0u;
        for (int i=t; i<306; i+=256){
            int bsel = (i >= 153), off = bsel ? i-153 : i;
            *(uint4*)((char*)(bsel ? n2b : n1b) + 6256 + off*16) = z;
        }
    }
    if (t < DN){
        float vv = vvec[t];
        sm[FACT+t] = __expf(vv*vv*(float)day_order[b]);
        sm[INFS+t] = infection[(size_t)bd*DN + t];
    }
    __syncthreads();

    {
        f32x4 acc2[2];
        { f32x4 z; z[0]=z[1]=z[2]=z[3]=0.f; acc2[0]=z; acc2[1]=z; }
        #pragma unroll
        for (int kt=0;kt<4;kt++){
            v8bf ah[2], al[2];
            #pragma unroll
            for (int mt=0;mt<2;mt++){
                int m = mt*16 + (l&15);
                int ko = (l>>4)*8 + kt*32;
                ah[mt] = *(const v8bf*)&xhl[0][m][ko];
                al[mt] = *(const v8bf*)&xhl[1][m][ko];
            }
            v8bf gh = gpk[(size_t)(w*4+kt)*64 + l];
            MFMA_(acc2[0], ah[0], gh);
            MFMA_(acc2[1], ah[1], gh);
            MFMA_(acc2[0], al[0], gh);
            MFMA_(acc2[1], al[1], gh);
        }
        int o = w*16 + (l&15);
        #pragma unroll
        for (int mt=0;mt<2;mt++){
            #pragma unroll
            for (int r=0;r<4;r++){
                int n = mt*16 + (l>>4)*4 + r;
                if (n < DN) sm[XW + n*64 + o] = acc2[mt][r];
            }
        }
    }

    if (t < DN){
        const float* ar = adj_real + (size_t)bd*(DN*DN) + t*DN;
        float s = 0.f;
        for (int m=0;m<DN;m++) s += ar[m];
        sm[DEG+t] = s;
    }

    {
        const int mat = w>>1;
        const int ntb = (w&1)*4;
        const float* bsrc = mat ? b2 : b1;
        float bias[4];
        #pragma unroll
        for (int q=0;q<4;q++) bias[q] = bsrc[(ntb+q)*16 + (l&15)];
        f32x4 acc[2][4];
        #pragma unroll
        for (int mt=0;mt<2;mt++)
            #pragma unroll
            for (int q=0;q<4;q++){ f32x4 z; z[0]=z[1]=z[2]=z[3]=0.f; acc[mt][q]=z; }
        #pragma unroll
        for (int kt=0;kt<4;kt++){
            v8bf ah[2], al[2];
            #pragma unroll
            for (int mt=0;mt<2;mt++){
                int m = mt*16 + (l&15);
                int ko = (l>>4)*8 + kt*32;
                ah[mt] = *(const v8bf*)&xhl[0][m][ko];
                al[mt] = *(const v8bf*)&xhl[1][m][ko];
            }
            #pragma unroll
            for (int q=0;q<4;q++){
                const v8bf* wb = wpk + ((size_t)(((mat*8+(ntb+q))*4+kt)*2)*64 + l);
                v8bf wh = wb[0], wl = wb[64];
                MFMA_(acc[0][q], ah[0], wh);
                MFMA_(acc[1][q], ah[1], wh);
                MFMA_(acc[0][q], al[0], wh);
                MFMA_(acc[1][q], al[1], wh);
                MFMA_(acc[0][q], ah[0], wl);
                MFMA_(acc[1][q], ah[1], wl);
            }
        }
        __syncthreads();

        unsigned short* dsth = mat ? n2b : n1b;
        unsigned short* dstl = mat ? n2l : n1l;
        #pragma unroll
        for (int mt=0;mt<2;mt++){
            #pragma unroll
            for (int q=0;q<4;q++){
                int fo = (ntb+q)*16 + (l&15);
                #pragma unroll
                for (int r=0;r<4;r++){
                    int n = mt*16 + (l>>4)*4 + r;
                    if (n < DN){
                        float nv = ftanh(acc[mt][q][r] + bias[q]);
                        unsigned short hb = f2bf(nv);
                        dsth[n*136 + fo] = hb;
                        dstl[n*136 + fo] = f2bf(nv - bf2f(hb));
                    }
                }
            }
        }
        {
            uint4 z; z.x=z.y=z.z=z.w=0u;
            for (int i=t; i<306; i+=256){
                int bsel = (i >= 153), off = bsel ? i-153 : i;
                *(uint4*)((char*)(bsel ? n2l : n1l) + 6256 + off*16) = z;
            }
        }
    }
    __syncthreads();

    {
        const int mt = w>>1, nt = w&1;
        f32x4 a3; a3[0]=a3[1]=a3[2]=a3[3]=0.f;
        #pragma unroll
        for (int kt=0;kt<4;kt++){
            int ar = (mt*16+(l&15))*136 + kt*32 + (l>>4)*8;
            int br = (nt*16+(l&15))*136 + kt*32 + (l>>4)*8;
            v8bf ah  = *(const v8bf*)&n1b[ar];
            v8bf alo = *(const v8bf*)&n1l[ar];
            v8bf bh  = *(const v8bf*)&n2b[br];
            v8bf blo = *(const v8bf*)&n2l[br];
            MFMA_(a3, ah,  bh);
            MFMA_(a3, alo, bh);
            MFMA_(a3, ah,  blo);
        }
        #pragma unroll
        for (int r=0;r<4;r++){
            int i = mt*16 + (l>>4)*4 + r;
            int j = nt*16 + (l&15);
            if (i < DN && j < DN) sm[S12 + i*24 + j] = a3[r];
        }
    }
    __syncthreads();

    for (int p=t; p<DN*DN; p+=256){
        int i=p/DN, j=p-i*DN;
        float al  = fmaxf(ftanh(sm[S12+i*24+j]-sm[S12+j*24+i]), 0.f);
        float md  = fsig(glp[i*DN+j]*sm[DEG+i]*sm[DEG+j]);
        float arv = adj_real[(size_t)bd*(DN*DN) + p];
        float adjv = al + md*arv;
        __builtin_nontemporal_store(adjv, &out_adj[(size_t)bd*(DN*DN) + p]);
        sm[ADJ + i*24 + j] = adjv + (i==j ? 1.f : 0.f);
    }
    __syncthreads();

    if (t<DN){
        float rs=0.f;
        for (int jj=0;jj<DN;jj++) rs += sm[ADJ+t*24+jj];
        sm[DINV+t] = rsqrtf(rs);
    }
    __syncthreads();

    for (int p=t;p<DN*DN;p+=256){
        int i=p/DN, j=p-i*DN;
        sm[ADJ+i*24+j] *= sm[DINV+i]*sm[DINV+j];
    }
    __syncthreads();

    for (int p=t;p<DN*64;p+=256){
        int n=p>>6, o=p&63;
        float a=0.f;
        #pragma unroll
        for (int m=0;m<DN;m++) a = fmaf(sm[ADJ+n*24+m], sm[XW+m*64+o], a);
        sm[GC + p] = fmaxf(a,0.f)*sm[FACT+n];
    }
    __syncthreads();

    for (int p=t; p<DN*18; p+=256){
        int n = p/18, r = p - n*18, hsel = r/9, k8 = r - hsel*9;
        __align__(16) unsigned short ob[8];
        #pragma unroll
        for (int e=0;e<8;e++){
            int k = k8*8+e;
            float v = (k<64) ? sm[GC + n*64 + k] : ((k==64) ? sm[INFS+n] : 0.f);
            unsigned short hb = f2bf(v);
            ob[e] = hsel ? f2bf(v - bf2f(hb)) : hb;
        }
        zlin4[(size_t)bd*414 + p] = *(const uint4*)ob;
    }
}

// ---------------------------------------------------------------------------
// Kernel B: MFMA LSTM.  grid=184, block=1024 (16 waves), 32 seqs/block.
// R15: one barrier per encoder step.  Parity-double-buffered H0 / U1h0 / U1h1.
// ps = step&1: ACT-L0 writes H0[ps],U1h0[ps]; L0 reads H0[ps^1], XB[ps];
// L1 reads U1h0[ps] + U1h1[ps^1]; ACT-L1 writes U1h1[ps]; FC reads U1h1[ps].
// ---------------------------------------------------------------------------
#define XB0O 0              // 4608
#define XB1O 4608           // ends 9216
#define H0O  9216           // 2 x 9728 (19 k8 slots; rows 16..18 stay zero)
#define U1H0 28672          // 2 x 8192
#define U1H1 45056          // 2 x 8192
#define X2O  61440          // [8][288] f32 = 9216
#define B0O  70656          // 512 f32
#define B1O  72704
#define FCO  74752          // 129 f32
#define INO  75272          // 32 f32
#define C0O  75408          // 4 x 1024 f32 = 16384
#define C1O  91792          // 16384
// end 108176

__global__ __launch_bounds__(1024, 2) void kernB(
    const uint4* __restrict__ zlin, const v8bf* __restrict__ w0p, const v8bf* __restrict__ w1p,
    const float* __restrict__ b0g, const float* __restrict__ b1g,
    const float* __restrict__ infection, const float* __restrict__ fcw,
    const float* __restrict__ fcb, float* __restrict__ outy)
{
    const int t = threadIdx.x, blk = blockIdx.x;
    const int w = t>>6, l = t&63;
    const int lhi = l>>4, llo = l&15;
    __shared__ __align__(16) unsigned char smraw[108176];
    char* smb = (char*)smraw;

    // zero H0..X2 end (9216..70656) and c-slots (75408..108176)
    {
        uint4 z; z.x=z.y=z.z=z.w=0u;
        for (int i = t; i < (70656-9216)/16; i += 1024) ((uint4*)(smb+9216))[i] = z;
        for (int i = t; i < (108176-75408)/16; i += 1024) ((uint4*)(smb+75408))[i] = z;
    }
    if (t < 512){
        ((float*)(smb+B0O))[t] = b0g[t];
        ((float*)(smb+B1O))[t] = b1g[t];
    }
    if (t < 129) ((float*)(smb+FCO))[t] = (t<128) ? fcw[t] : fcb[0];
    if (t < 32){
        int gseq = blk*32 + t, n = gseq>>8, bb = gseq&255;
        float a = 0.f;
        for (int dd=0; dd<DD; dd++)
            a = fmaf(fcw[128+dd], infection[((size_t)bb*DD+dd)*DN+n], a);
        ((float*)(smb+INO))[t] = a;
    }

    int k81 = t >> 5, sq1 = t & 31;
    int gs1 = blk*32 + sq1;
    size_t cb1 = (size_t)(gs1 & 255)*DD*414 + (gs1>>8)*18 + k81;   // hsel=0
    int d1 = t*16;

    const int mt0 = 2*w;
    const int jt  = mt0>>2, r3 = mt0&3;
    const int j8  = jt*2 + (lhi>>1);
    const int sub = (lhi&1)*8 + r3*2;
    const int j0  = jt*16 + lhi*4 + r3;

    __syncthreads();

    // prologue: stage x(0) into XB0 (parity 0)
    if (t < 288){
        uint4 a0 = ntload4(zlin + cb1);
        *(uint4*)(smb + XB0O + d1) = a0;
    }
    __syncthreads();

    const float* bias0L = (const float*)(smb+B0O);
    const float* bias1L = (const float*)(smb+B1O);

    for (int step = 0; step < DD + DY; ++step){
        const int ps  = step & 1;
        const int xb  = ps ? XB1O : XB0O;
        const int xbn = ps ? XB0O : XB1O;
        const bool do_stage = (step + 1 < DD);
        const char* h0rd  = smb + H0O  + (ps^1)*9728;
        char*       h0wr  = smb + H0O  + ps*9728;
        char*       u1h0  = smb + U1H0 + ps*8192;       // write+read this step
        const char* u1h1r = smb + U1H1 + (ps^1)*8192;   // h1(s-1)
        char*       u1h1w = smb + U1H1 + ps*8192;

        // ---------------- L0 MFMA (+ stage x(step+1)) ----------------
        {
            uint4 sv0; sv0.x=sv0.y=sv0.z=sv0.w=0u;
            if (do_stage && t < 288)
                sv0 = ntload4(zlin + (size_t)(step+1)*414 + cb1);

            f32x4 acc[2][2];
            #pragma unroll
            for (int mi=0;mi<2;mi++){
                int j = j0 + mi;
                f32x4 a;
                a[0]=bias0L[j]; a[1]=bias0L[128+j]; a[2]=bias0L[256+j]; a[3]=bias0L[384+j];
                acc[mi][0] = a; acc[mi][1] = a;
            }
            #pragma unroll 2
            for (int kt=0; kt<7; ++kt){
                const v8bf* wrow = w0p + (size_t)(kt*32 + mt0)*64 + l;
                v8bf A0 = wrow[0], A1 = wrow[64];
                int k8 = kt*4 + lhi;
                bool inx = (k8 <= 8);
                const char* hib = inx ? (smb + xb + k8*512) : (h0rd + (k8-9)*512);
                v8bf BH0 = *(const v8bf*)(hib + llo*16);
                v8bf BH1 = *(const v8bf*)(hib + 256 + llo*16);
                MFMA_(acc[0][0], A0, BH0);
                MFMA_(acc[1][0], A1, BH0);
                MFMA_(acc[0][1], A0, BH1);
                MFMA_(acc[1][1], A1, BH1);
            }
            if (do_stage && t < 288)
                *(uint4*)(smb + xbn + d1) = sv0;

            // x2 accumulation (own slice of xb; no cross-thread dep)
            if (step < DD && t < 288){
                const unsigned short* hp = (const unsigned short*)(smb + xb + t*16);
                float* xs = (float*)(smb + X2O);
                #pragma unroll
                for (int e=0;e<8;e++) xs[e*288+t] += bf2f(hp[e]);
            }

            // ACT L0 -> h0(step) into H0[ps] + U1h0[ps]
            #pragma unroll
            for (int nt=0;nt<2;nt++){
                unsigned short hh[2];
                #pragma unroll
                for (int mi=0;mi<2;mi++){
                    float* cslot = (float*)(smb + C0O) + (mi*2+nt)*1024 + t;
                    f32x4 a = acc[mi][nt];
                    float ii = fsig(a[0]), ff = fsig(a[1]), gg = ftanh(a[2]), oo = fsig(a[3]);
                    float c = ff*cslot[0] + ii*gg;
                    cslot[0] = c;
                    hh[mi] = f2bf(oo*ftanh(c));
                }
                unsigned ph = (unsigned)hh[0] | ((unsigned)hh[1]<<16);
                int bo = j8*512 + (nt*16+llo)*16 + sub;
                *(unsigned*)(h0wr + bo) = ph;
                *(unsigned*)(u1h0 + bo) = ph;
            }
            __syncthreads();   // THE barrier: h0 visible; staging visible for s+1
        }

        // ---------------- L1 MFMA ----------------
        {
            f32x4 acc1[2][2];
            #pragma unroll
            for (int mi=0;mi<2;mi++){
                int j = j0 + mi;
                f32x4 a;
                a[0]=bias1L[j]; a[1]=bias1L[128+j]; a[2]=bias1L[256+j]; a[3]=bias1L[384+j];
                acc1[mi][0] = a; acc1[mi][1] = a;
            }
            #pragma unroll 2
            for (int kt=0; kt<8; ++kt){
                const v8bf* wrow = w1p + (size_t)(kt*32 + mt0)*64 + l;
                v8bf A0 = wrow[0], A1 = wrow[64];
                int k8 = kt*4 + lhi;
                const char* hib = (k8 < 16) ? (u1h0 + k8*512) : (u1h1r + (k8-16)*512);
                v8bf BH0 = *(const v8bf*)(hib + llo*16);
                v8bf BH1 = *(const v8bf*)(hib + 256 + llo*16);
                MFMA_(acc1[0][0], A0, BH0);
                MFMA_(acc1[1][0], A1, BH0);
                MFMA_(acc1[0][1], A0, BH1);
                MFMA_(acc1[1][1], A1, BH1);
            }

            // ACT L1 -> h1(step) into U1h1[ps]  (no barrier needed: own-wave acc,
            // writes go to parity region no other wave reads this step)
            #pragma unroll
            for (int nt=0;nt<2;nt++){
                unsigned short hh[2];
                #pragma unroll
                for (int mi=0;mi<2;mi++){
                    float* cslot = (float*)(smb + C1O) + (mi*2+nt)*1024 + t;
                    f32x4 a = acc1[mi][nt];
                    float ii = fsig(a[0]), ff = fsig(a[1]), gg = ftanh(a[2]), oo = fsig(a[3]);
                    float c = ff*cslot[0] + ii*gg;
                    cslot[0] = c;
                    hh[mi] = f2bf(oo*ftanh(c));
                }
                unsigned ph = (unsigned)hh[0] | ((unsigned)hh[1]<<16);
                int bo = j8*512 + (nt*16+llo)*16 + sub;
                *(unsigned*)(u1h1w + bo) = ph;
            }
        }

        // ---- step 27: build decoder mean input into BOTH XB buffers
        if (step == DD-1){
            __syncthreads();
            if (t < 288){
                const float* xs = (const float*)(smb + X2O);
                __align__(16) unsigned short hb8[8];
                #pragma unroll
                for (int e=0;e<8;e++) hb8[e] = f2bf(xs[e*288+t] * (1.f/(float)DD));
                *(uint4*)(smb + XB0O + t*16) = *(const uint4*)hb8;
                *(uint4*)(smb + XB1O + t*16) = *(const uint4*)hb8;
            }
            __syncthreads();
        }

        // ---- decoder FC (reads h1(step) = U1h1[ps])
        if (step >= DD){
            __syncthreads();   // all waves' ACT-L1 writes visible
            if (t < 256){
                int seq = t>>3, l8 = t&7;
                const unsigned short* uh = (const unsigned short*)(smb + U1H1 + ps*8192);
                const float* fw = (const float*)(smb+FCO);
                float a = 0.f;
                #pragma unroll
                for (int half=0; half<2; ++half){
                    int k8 = l8*2 + half;
                    int base = (k8*32 + seq)*8;
                    #pragma unroll
                    for (int e=0;e<8;e++){
                        int j = l8*16 + half*8 + e;
                        a = fmaf(fw[j], bf2f(uh[base+e]), a);
                    }
                }
                a += __shfl_down(a, 4, 8);
                a += __shfl_down(a, 2, 8);
                a += __shfl_down(a, 1, 8);
                if (l8 == 0){
                    int gseq = blk*32 + seq, n = gseq>>8, bb = gseq&255;
                    float yv = fmaxf(a + ((const float*)(smb+INO))[seq] + fw[128], 0.f);
                    __builtin_nontemporal_store(yv, &outy[((size_t)bb*DY + (step-DD))*DN + n]);
                }
            }
        }
        // no closing barrier: all cross-step hazards gated by next step's barrier
    }
}

// ---------------------------------------------------------------------------
extern "C" void kernel_launch(void* const* d_in, const int* in_sizes, int n_in,
                              void* d_out, int out_size, void* d_ws, size_t ws_size,
                              hipStream_t stream)
{
    const float* x         = (const float*)d_in[0];
    const float* adj_real  = (const float*)d_in[1];
    const float* infection = (const float*)d_in[2];
    const int*   day_order = (const int*)  d_in[3];
    const float* gl_w1     = (const float*)d_in[4];
    const float* gl_b1     = (const float*)d_in[5];
    const float* gl_w2     = (const float*)d_in[6];
    const float* gl_b2     = (const float*)d_in[7];
    const float* glp       = (const float*)d_in[8];
    const float* gcn_w     = (const float*)d_in[9];
    const float* vvec      = (const float*)d_in[10];
    const float* wih0      = (const float*)d_in[11];
    const float* whh0      = (const float*)d_in[12];
    const float* b0        = (const float*)d_in[13];
    const float* wih1      = (const float*)d_in[14];
    const float* whh1      = (const float*)d_in[15];
    const float* b1        = (const float*)d_in[16];
    const float* fcw       = (const float*)d_in[17];
    const float* fcb       = (const float*)d_in[18];

    uint8_t* wsb = (uint8_t*)d_ws;
    uint4*          zlin = (uint4*)(wsb);
    unsigned short* wb0  = (unsigned short*)(wsb + WB0_OFF);
    unsigned short* wb1  = (unsigned short*)(wsb + WB1_OFF);
    unsigned short* wpk  = (unsigned short*)(wsb + WPK_OFF);
    unsigned short* gpk  = (unsigned short*)(wsb + GPK_OFF);
    float* out_adj = (float*)d_out;
    float* out_y   = out_adj + ADJSZ;

    kernPrep<<<dim3(1248), dim3(256), 0, stream>>>(wih0, whh0, wih1, whh1,
                                                   gl_w1, gl_w2, gcn_w,
                                                   wb0, wb1, wpk, gpk);
    kernA<<<dim3(DB*DD), dim3(256), 0, stream>>>(x, adj_real, infection, day_order,
                                                 gl_b1, gl_b2, glp, vvec,
                                                 (const v8bf*)wpk, (const v8bf*)gpk,
                                                 out_adj, zlin);
    kernB<<<dim3(GBLK), dim3(1024), 0, stream>>>(zlin, (const v8bf*)wb0,
                                                 (const v8bf*)wb1, b0, b1, infection,
                                                 fcw, fcb, out_y);
}

// Round 16
// 421.889 us; speedup vs baseline: 1.6561x; 1.0251x over previous
//
#include <hip/hip_runtime.h>
#include <hip/hip_bf16.h>
#include <stdint.h>

// ---------------------------------------------------------------------------
// B=256 D=28 N=23 F=128 O=64 H=128 Y=7.  NBSEQ=5888 = 184 blocks x 32 seqs.
// R16 (kernB only; kernA/prep unchanged R14):
//  - H0 surface merged into U1h0 parity buffers (h0 written ONCE; L0 reads
//    h0(s-1) from U1h0[ps^1] slots (k8-9); slots 16..18 stay zero = K-pad).
//  - c-states re-laid [t][4] -> one b128 read + one b128 write per layer.
//  - biases re-laid [j][g] -> two b128 reads per layer (was 8 b32).
//  - h packing via v_cvt_pk_bf16_f32 (1 op, RNE) instead of 2x f2bf + or/shl.
//  LDS 108 -> 92KB.  One barrier per encoder step (R15 scheme preserved).
// ---------------------------------------------------------------------------

#define DB 256
#define DD 28
#define DN 23
#define DF 128
#define DO 64
#define DH 128
#define DY 7
#define NBSEQ (DN*DB)
#define ADJSZ (DB*DD*DN*DN)
#define GBLK 184

// workspace byte offsets
#define WB0_OFF   47480832u            // zlin = 7168*414*16
#define WB1_OFF   47710208u
#define WPK_OFF   47972352u
#define GPK_OFF   48103424u

using v8bf  = __attribute__((ext_vector_type(8))) __bf16;
using f32x4 = __attribute__((ext_vector_type(4))) float;
using u32x4 = __attribute__((ext_vector_type(4))) unsigned int;

__device__ __forceinline__ float fsig(float x)  { return 1.f/(1.f+__expf(-x)); }
__device__ __forceinline__ float ftanh(float x) { return 1.f - 2.f/(__expf(2.f*x)+1.f); }

__device__ __forceinline__ unsigned short f2bf(float f){
    unsigned u = __builtin_bit_cast(unsigned, f);
    return (unsigned short)((u + 0x7FFFu + ((u>>16)&1u)) >> 16);
}
__device__ __forceinline__ float bf2f(unsigned short b){
    return __builtin_bit_cast(float, (unsigned)b << 16);
}
__device__ __forceinline__ uint4 ntload4(const uint4* p){
    u32x4 v = __builtin_nontemporal_load((const u32x4*)p);
    return *(uint4*)&v;
}
__device__ __forceinline__ unsigned pkbf(float lo, float hi){
    unsigned r;
    asm("v_cvt_pk_bf16_f32 %0, %1, %2" : "=v"(r) : "v"(lo), "v"(hi));
    return r;
}

#define MFMA_(acc_, A_, B_) acc_ = __builtin_amdgcn_mfma_f32_16x16x32_bf16(A_, B_, acc_, 0, 0, 0)

// ---------------------------------------------------------------------------
// Prep (unchanged)
// ---------------------------------------------------------------------------
__global__ __launch_bounds__(256) void kernPrep(
    const float* __restrict__ wih0, const float* __restrict__ whh0,
    const float* __restrict__ wih1, const float* __restrict__ whh1,
    const float* __restrict__ glw1, const float* __restrict__ glw2,
    const float* __restrict__ gcn_w,
    unsigned short* __restrict__ wb0, unsigned short* __restrict__ wb1,
    unsigned short* __restrict__ wpk, unsigned short* __restrict__ gpk)
{
    int idx = blockIdx.x*256 + threadIdx.x;
    if (idx < 114688){
        int e = idx&7, l = (idx>>3)&63, mt = (idx>>9)&31, kt = idx>>14;
        int rit = l&15, lj = rit>>2, g = rit&3;
        int r = g*128 + (mt>>2)*16 + lj*4 + (mt&3);
        int k = kt*32 + (l>>4)*8 + e;
        float v = 0.f;
        if (k < 65)                  v = wih0[r*65 + k];
        else if (k >= 72 && k < 200) v = whh0[r*128 + (k-72)];
        wb0[idx] = f2bf(v);
        return;
    }
    idx -= 114688;
    if (idx < 131072){
        int e = idx&7, l = (idx>>3)&63, mt = (idx>>9)&31, kt = idx>>14;
        int rit = l&15, lj = rit>>2, g = rit&3;
        int r = g*128 + (mt>>2)*16 + lj*4 + (mt&3);
        int k = kt*32 + (l>>4)*8 + e;
        float v = (k < 128) ? wih1[r*128 + k] : whh1[r*128 + (k-128)];
        wb1[idx] = f2bf(v);
        return;
    }
    idx -= 131072;
    if (idx < 65536){
        int e = idx&7, l = (idx>>3)&63, hsel = (idx>>9)&1, kt = (idx>>10)&3,
            nt = (idx>>12)&7, mat = (idx>>15)&1;
        int fo = nt*16 + (l&15);
        int k  = kt*32 + (l>>4)*8 + e;
        float v = (mat ? glw2 : glw1)[fo*128 + k];
        unsigned short hb = f2bf(v);
        wpk[idx] = hsel ? f2bf(v - bf2f(hb)) : hb;
        return;
    }
    idx -= 65536;
    if (idx < 8192){
        int e = idx&7, l = (idx>>3)&63, kt = (idx>>9)&3, nt = (idx>>11)&3;
        int o = nt*16 + (l&15);
        int k = kt*32 + (l>>4)*8 + e;
        gpk[idx] = f2bf(gcn_w[k*64 + o]);
    }
}

// ---------------------------------------------------------------------------
// Kernel A (unchanged R14): per-(b,d) graph stage -> adj + zlin[bd][414].
// ---------------------------------------------------------------------------
__global__ __launch_bounds__(256) void kernA(
    const float* __restrict__ x, const float* __restrict__ adj_real,
    const float* __restrict__ infection, const int* __restrict__ day_order,
    const float* __restrict__ b1, const float* __restrict__ b2,
    const float* __restrict__ glp, const float* __restrict__ vvec,
    const v8bf* __restrict__ wpk, const v8bf* __restrict__ gpk,
    float* __restrict__ out_adj, uint4* __restrict__ zlin4)
{
    const int bd = blockIdx.x;
    const int b  = bd / DD;
    const int t  = threadIdx.x;
    const int w  = t>>6, l = t&63;

    __shared__ float sm[4140];
    const int S12=0, ADJ=552, XW=1104, DEG=2576, DINV=2599, FACT=2622,
              INFS=2645, GC=2668;
    __shared__ __align__(16) unsigned short xhl[2][32][140];
    __shared__ __align__(16) unsigned short n1b[32*136];
    __shared__ __align__(16) unsigned short n2b[32*136];
    unsigned short* n1l = &xhl[0][0][0];
    unsigned short* n2l = n1l + 32*136;

    const float* xg = x + (size_t)bd*(DN*DF);
    for (int p=t; p<DN*DF; p+=256){
        int n = p>>7, k = p&127;
        float v = xg[p];
        unsigned short hb = f2bf(v);
        xhl[0][n][k] = hb;
        xhl[1][n][k] = f2bf(v - bf2f(hb));
    }
    for (int p=t; p<9*DF; p+=256){
        int n = DN + (p>>7), k = p&127;
        xhl[0][n][k] = 0; xhl[1][n][k] = 0;
    }
    {
        uint4 z; z.x=z.y=z.z=z.w=0u;
        for (int i=t; i<306; i+=256){
            int bsel = (i >= 153), off = bsel ? i-153 : i;
            *(uint4*)((char*)(bsel ? n2b : n1b) + 6256 + off*16) = z;
        }
    }
    if (t < DN){
        float vv = vvec[t];
        sm[FACT+t] = __expf(vv*vv*(float)day_order[b]);
        sm[INFS+t] = infection[(size_t)bd*DN + t];
    }
    __syncthreads();

    {
        f32x4 acc2[2];
        { f32x4 z; z[0]=z[1]=z[2]=z[3]=0.f; acc2[0]=z; acc2[1]=z; }
        #pragma unroll
        for (int kt=0;kt<4;kt++){
            v8bf ah[2], al[2];
            #pragma unroll
            for (int mt=0;mt<2;mt++){
                int m = mt*16 + (l&15);
                int ko = (l>>4)*8 + kt*32;
                ah[mt] = *(const v8bf*)&xhl[0][m][ko];
                al[mt] = *(const v8bf*)&xhl[1][m][ko];
            }
            v8bf gh = gpk[(size_t)(w*4+kt)*64 + l];
            MFMA_(acc2[0], ah[0], gh);
            MFMA_(acc2[1], ah[1], gh);
            MFMA_(acc2[0], al[0], gh);
            MFMA_(acc2[1], al[1], gh);
        }
        int o = w*16 + (l&15);
        #pragma unroll
        for (int mt=0;mt<2;mt++){
            #pragma unroll
            for (int r=0;r<4;r++){
                int n = mt*16 + (l>>4)*4 + r;
                if (n < DN) sm[XW + n*64 + o] = acc2[mt][r];
            }
        }
    }

    if (t < DN){
        const float* ar = adj_real + (size_t)bd*(DN*DN) + t*DN;
        float s = 0.f;
        for (int m=0;m<DN;m++) s += ar[m];
        sm[DEG+t] = s;
    }

    {
        const int mat = w>>1;
        const int ntb = (w&1)*4;
        const float* bsrc = mat ? b2 : b1;
        float bias[4];
        #pragma unroll
        for (int q=0;q<4;q++) bias[q] = bsrc[(ntb+q)*16 + (l&15)];
        f32x4 acc[2][4];
        #pragma unroll
        for (int mt=0;mt<2;mt++)
            #pragma unroll
            for (int q=0;q<4;q++){ f32x4 z; z[0]=z[1]=z[2]=z[3]=0.f; acc[mt][q]=z; }
        #pragma unroll
        for (int kt=0;kt<4;kt++){
            v8bf ah[2], al[2];
            #pragma unroll
            for (int mt=0;mt<2;mt++){
                int m = mt*16 + (l&15);
                int ko = (l>>4)*8 + kt*32;
                ah[mt] = *(const v8bf*)&xhl[0][m][ko];
                al[mt] = *(const v8bf*)&xhl[1][m][ko];
            }
            #pragma unroll
            for (int q=0;q<4;q++){
                const v8bf* wb = wpk + ((size_t)(((mat*8+(ntb+q))*4+kt)*2)*64 + l);
                v8bf wh = wb[0], wl = wb[64];
                MFMA_(acc[0][q], ah[0], wh);
                MFMA_(acc[1][q], ah[1], wh);
                MFMA_(acc[0][q], al[0], wh);
                MFMA_(acc[1][q], al[1], wh);
                MFMA_(acc[0][q], ah[0], wl);
                MFMA_(acc[1][q], ah[1], wl);
            }
        }
        __syncthreads();

        unsigned short* dsth = mat ? n2b : n1b;
        unsigned short* dstl = mat ? n2l : n1l;
        #pragma unroll
        for (int mt=0;mt<2;mt++){
            #pragma unroll
            for (int q=0;q<4;q++){
                int fo = (ntb+q)*16 + (l&15);
                #pragma unroll
                for (int r=0;r<4;r++){
                    int n = mt*16 + (l>>4)*4 + r;
                    if (n < DN){
                        float nv = ftanh(acc[mt][q][r] + bias[q]);
                        unsigned short hb = f2bf(nv);
                        dsth[n*136 + fo] = hb;
                        dstl[n*136 + fo] = f2bf(nv - bf2f(hb));
                    }
                }
            }
        }
        {
            uint4 z; z.x=z.y=z.z=z.w=0u;
            for (int i=t; i<306; i+=256){
                int bsel = (i >= 153), off = bsel ? i-153 : i;
                *(uint4*)((char*)(bsel ? n2l : n1l) + 6256 + off*16) = z;
            }
        }
    }
    __syncthreads();

    {
        const int mt = w>>1, nt = w&1;
        f32x4 a3; a3[0]=a3[1]=a3[2]=a3[3]=0.f;
        #pragma unroll
        for (int kt=0;kt<4;kt++){
            int ar = (mt*16+(l&15))*136 + kt*32 + (l>>4)*8;
            int br = (nt*16+(l&15))*136 + kt*32 + (l>>4)*8;
            v8bf ah  = *(const v8bf*)&n1b[ar];
            v8bf alo = *(const v8bf*)&n1l[ar];
            v8bf bh  = *(const v8bf*)&n2b[br];
            v8bf blo = *(const v8bf*)&n2l[br];
            MFMA_(a3, ah,  bh);
            MFMA_(a3, alo, bh);
            MFMA_(a3, ah,  blo);
        }
        #pragma unroll
        for (int r=0;r<4;r++){
            int i = mt*16 + (l>>4)*4 + r;
            int j = nt*16 + (l&15);
            if (i < DN && j < DN) sm[S12 + i*24 + j] = a3[r];
        }
    }
    __syncthreads();

    for (int p=t; p<DN*DN; p+=256){
        int i=p/DN, j=p-i*DN;
        float al  = fmaxf(ftanh(sm[S12+i*24+j]-sm[S12+j*24+i]), 0.f);
        float md  = fsig(glp[i*DN+j]*sm[DEG+i]*sm[DEG+j]);
        float arv = adj_real[(size_t)bd*(DN*DN) + p];
        float adjv = al + md*arv;
        __builtin_nontemporal_store(adjv, &out_adj[(size_t)bd*(DN*DN) + p]);
        sm[ADJ + i*24 + j] = adjv + (i==j ? 1.f : 0.f);
    }
    __syncthreads();

    if (t<DN){
        float rs=0.f;
        for (int jj=0;jj<DN;jj++) rs += sm[ADJ+t*24+jj];
        sm[DINV+t] = rsqrtf(rs);
    }
    __syncthreads();

    for (int p=t;p<DN*DN;p+=256){
        int i=p/DN, j=p-i*DN;
        sm[ADJ+i*24+j] *= sm[DINV+i]*sm[DINV+j];
    }
    __syncthreads();

    for (int p=t;p<DN*64;p+=256){
        int n=p>>6, o=p&63;
        float a=0.f;
        #pragma unroll
        for (int m=0;m<DN;m++) a = fmaf(sm[ADJ+n*24+m], sm[XW+m*64+o], a);
        sm[GC + p] = fmaxf(a,0.f)*sm[FACT+n];
    }
    __syncthreads();

    for (int p=t; p<DN*18; p+=256){
        int n = p/18, r = p - n*18, hsel = r/9, k8 = r - hsel*9;
        __align__(16) unsigned short ob[8];
        #pragma unroll
        for (int e=0;e<8;e++){
            int k = k8*8+e;
            float v = (k<64) ? sm[GC + n*64 + k] : ((k==64) ? sm[INFS+n] : 0.f);
            unsigned short hb = f2bf(v);
            ob[e] = hsel ? f2bf(v - bf2f(hb)) : hb;
        }
        zlin4[(size_t)bd*414 + p] = *(const uint4*)ob;
    }
}

// ---------------------------------------------------------------------------
// Kernel B: MFMA LSTM.  grid=184, block=1024 (16 waves), 32 seqs/block.
// R16 LDS map (92KB): single h0 surface U1H0 (19 slots/parity, 16..18 zero),
// c as [t][4] f32x4, bias as [j][g] f32x4.  One barrier per encoder step.
// ---------------------------------------------------------------------------
#define XB0O 0              // 4608
#define XB1O 4608           // -> 9216
#define U1H0 9216           // 2 x 9728 = 19456 -> 28672
#define U1H1 28672          // 2 x 8192 = 16384 -> 45056
#define X2O  45056          // [8][288] f32 = 9216 -> 54272
#define B0O  54272          // 512 f32 [j][g] -> 56320
#define B1O  56320          // -> 58368
#define FCO  58368          // 129 f32 -> 58884 (pad 58896)
#define INO  58896          // 32 f32 -> 59024
#define C0O  59024          // 1024 x 16B = 16384 -> 75408
#define C1O  75408          // 16384 -> 91792
// end 91792

__global__ __launch_bounds__(1024, 2) void kernB(
    const uint4* __restrict__ zlin, const v8bf* __restrict__ w0p, const v8bf* __restrict__ w1p,
    const float* __restrict__ b0g, const float* __restrict__ b1g,
    const float* __restrict__ infection, const float* __restrict__ fcw,
    const float* __restrict__ fcb, float* __restrict__ outy)
{
    const int t = threadIdx.x, blk = blockIdx.x;
    const int w = t>>6, l = t&63;
    const int lhi = l>>4, llo = l&15;
    __shared__ __align__(16) unsigned char smraw[91792];
    char* smb = (char*)smraw;

    // zero U1H0..X2 end (9216..54272) and c-slots (59024..91792)
    {
        uint4 z; z.x=z.y=z.z=z.w=0u;
        for (int i = t; i < (54272-9216)/16; i += 1024) ((uint4*)(smb+9216))[i] = z;
        for (int i = t; i < (91792-59024)/16; i += 1024) ((uint4*)(smb+59024))[i] = z;
    }
    if (t < 512){
        // bias [j][g]: idx = j*4+g  <-  b*g[g*128+j]
        ((float*)(smb+B0O))[t] = b0g[(t&3)*128 + (t>>2)];
        ((float*)(smb+B1O))[t] = b1g[(t&3)*128 + (t>>2)];
    }
    if (t < 129) ((float*)(smb+FCO))[t] = (t<128) ? fcw[t] : fcb[0];
    if (t < 32){
        int gseq = blk*32 + t, n = gseq>>8, bb = gseq&255;
        float a = 0.f;
        for (int dd=0; dd<DD; dd++)
            a = fmaf(fcw[128+dd], infection[((size_t)bb*DD+dd)*DN+n], a);
        ((float*)(smb+INO))[t] = a;
    }

    int k81 = t >> 5, sq1 = t & 31;
    int gs1 = blk*32 + sq1;
    size_t cb1 = (size_t)(gs1 & 255)*DD*414 + (gs1>>8)*18 + k81;   // hsel=0
    int d1 = t*16;

    const int mt0 = 2*w;
    const int jt  = mt0>>2, r3 = mt0&3;
    const int j8  = jt*2 + (lhi>>1);
    const int sub = (lhi&1)*8 + r3*2;
    const int j0  = jt*16 + lhi*4 + r3;

    __syncthreads();

    // prologue: stage x(0) into XB0 (parity 0)
    if (t < 288){
        uint4 a0 = ntload4(zlin + cb1);
        *(uint4*)(smb + XB0O + d1) = a0;
    }
    __syncthreads();

    for (int step = 0; step < DD + DY; ++step){
        const int ps  = step & 1;
        const int xb  = ps ? XB1O : XB0O;
        const int xbn = ps ? XB0O : XB1O;
        const bool do_stage = (step + 1 < DD);
        const char* h0rd = smb + U1H0 + (ps^1)*9728;    // h0(s-1), slots (k8-9)
        char*       h0wr = smb + U1H0 + ps*9728;        // h0(s): write + L1 read
        const char* h1rd = smb + U1H1 + (ps^1)*8192;    // h1(s-1)
        char*       h1wr = smb + U1H1 + ps*8192;

        // ---------------- L0 MFMA (+ stage x(step+1)) ----------------
        {
            uint4 sv0; sv0.x=sv0.y=sv0.z=sv0.w=0u;
            if (do_stage && t < 288)
                sv0 = ntload4(zlin + (size_t)(step+1)*414 + cb1);

            f32x4 acc[2][2];
            #pragma unroll
            for (int mi=0;mi<2;mi++){
                f32x4 bv = *(const f32x4*)(smb + B0O + (j0+mi)*16);
                acc[mi][0] = bv; acc[mi][1] = bv;
            }
            #pragma unroll 2
            for (int kt=0; kt<7; ++kt){
                const v8bf* wrow = w0p + (size_t)(kt*32 + mt0)*64 + l;
                v8bf A0 = wrow[0], A1 = wrow[64];
                int k8 = kt*4 + lhi;
                bool inx = (k8 <= 8);
                const char* hib = inx ? (smb + xb + k8*512) : (h0rd + (k8-9)*512);
                v8bf BH0 = *(const v8bf*)(hib + llo*16);
                v8bf BH1 = *(const v8bf*)(hib + 256 + llo*16);
                MFMA_(acc[0][0], A0, BH0);
                MFMA_(acc[1][0], A1, BH0);
                MFMA_(acc[0][1], A0, BH1);
                MFMA_(acc[1][1], A1, BH1);
            }
            if (do_stage && t < 288)
                *(uint4*)(smb + xbn + d1) = sv0;

            // x2 accumulation (own slice of xb)
            if (step < DD && t < 288){
                const unsigned short* hp = (const unsigned short*)(smb + xb + t*16);
                float* xs = (float*)(smb + X2O);
                #pragma unroll
                for (int e=0;e<8;e++) xs[e*288+t] += bf2f(hp[e]);
            }

            // ACT L0 -> h0(step) into U1H0[ps] only
            {
                f32x4 c0v = *(const f32x4*)(smb + C0O + t*16);
                #pragma unroll
                for (int nt=0;nt<2;nt++){
                    float hf[2];
                    #pragma unroll
                    for (int mi=0;mi<2;mi++){
                        f32x4 a = acc[mi][nt];
                        float ii = fsig(a[0]), ff = fsig(a[1]), gg = ftanh(a[2]), oo = fsig(a[3]);
                        float c = ff*c0v[mi*2+nt] + ii*gg;
                        c0v[mi*2+nt] = c;
                        hf[mi] = oo*ftanh(c);
                    }
                    unsigned ph = pkbf(hf[0], hf[1]);
                    int bo = j8*512 + (nt*16+llo)*16 + sub;
                    *(unsigned*)(h0wr + bo) = ph;
                }
                *(f32x4*)(smb + C0O + t*16) = c0v;
            }
            __syncthreads();   // THE barrier
        }

        // ---------------- L1 MFMA ----------------
        {
            f32x4 acc1[2][2];
            #pragma unroll
            for (int mi=0;mi<2;mi++){
                f32x4 bv = *(const f32x4*)(smb + B1O + (j0+mi)*16);
                acc1[mi][0] = bv; acc1[mi][1] = bv;
            }
            #pragma unroll 2
            for (int kt=0; kt<8; ++kt){
                const v8bf* wrow = w1p + (size_t)(kt*32 + mt0)*64 + l;
                v8bf A0 = wrow[0], A1 = wrow[64];
                int k8 = kt*4 + lhi;
                const char* hib = (k8 < 16) ? (h0wr + k8*512) : (h1rd + (k8-16)*512);
                v8bf BH0 = *(const v8bf*)(hib + llo*16);
                v8bf BH1 = *(const v8bf*)(hib + 256 + llo*16);
                MFMA_(acc1[0][0], A0, BH0);
                MFMA_(acc1[1][0], A1, BH0);
                MFMA_(acc1[0][1], A0, BH1);
                MFMA_(acc1[1][1], A1, BH1);
            }

            // ACT L1 -> h1(step) into U1H1[ps]
            {
                f32x4 c1v = *(const f32x4*)(smb + C1O + t*16);
                #pragma unroll
                for (int nt=0;nt<2;nt++){
                    float hf[2];
                    #pragma unroll
                    for (int mi=0;mi<2;mi++){
                        f32x4 a = acc1[mi][nt];
                        float ii = fsig(a[0]), ff = fsig(a[1]), gg = ftanh(a[2]), oo = fsig(a[3]);
                        float c = ff*c1v[mi*2+nt] + ii*gg;
                        c1v[mi*2+nt] = c;
                        hf[mi] = oo*ftanh(c);
                    }
                    unsigned ph = pkbf(hf[0], hf[1]);
                    int bo = j8*512 + (nt*16+llo)*16 + sub;
                    *(unsigned*)(h1wr + bo) = ph;
                }
                *(f32x4*)(smb + C1O + t*16) = c1v;
            }
        }

        // ---- step 27: build decoder mean input into BOTH XB buffers
        if (step == DD-1){
            __syncthreads();
            if (t < 288){
                const float* xs = (const float*)(smb + X2O);
                __align__(16) unsigned short hb8[8];
                #pragma unroll
                for (int e=0;e<8;e++) hb8[e] = f2bf(xs[e*288+t] * (1.f/(float)DD));
                *(uint4*)(smb + XB0O + t*16) = *(const uint4*)hb8;
                *(uint4*)(smb + XB1O + t*16) = *(const uint4*)hb8;
            }
            __syncthreads();
        }

        // ---- decoder FC (reads h1(step) = U1H1[ps])
        if (step >= DD){
            __syncthreads();
            if (t < 256){
                int seq = t>>3, l8 = t&7;
                const unsigned short* uh = (const unsigned short*)(smb + U1H1 + ps*8192);
                const float* fw = (const float*)(smb+FCO);
                float a = 0.f;
                #pragma unroll
                for (int half=0; half<2; ++half){
                    int k8 = l8*2 + half;
                    int base = (k8*32 + seq)*8;
                    #pragma unroll
                    for (int e=0;e<8;e++){
                        int j = l8*16 + half*8 + e;
                        a = fmaf(fw[j], bf2f(uh[base+e]), a);
                    }
                }
                a += __shfl_down(a, 4, 8);
                a += __shfl_down(a, 2, 8);
                a += __shfl_down(a, 1, 8);
                if (l8 == 0){
                    int gseq = blk*32 + seq, n = gseq>>8, bb = gseq&255;
                    float yv = fmaxf(a + ((const float*)(smb+INO))[seq] + fw[128], 0.f);
                    __builtin_nontemporal_store(yv, &outy[((size_t)bb*DY + (step-DD))*DN + n]);
                }
            }
        }
        // no closing barrier: hazards gated by next step's barrier chain
    }
}

// ---------------------------------------------------------------------------
extern "C" void kernel_launch(void* const* d_in, const int* in_sizes, int n_in,
                              void* d_out, int out_size, void* d_ws, size_t ws_size,
                              hipStream_t stream)
{
    const float* x         = (const float*)d_in[0];
    const float* adj_real  = (const float*)d_in[1];
    const float* infection = (const float*)d_in[2];
    const int*   day_order = (const int*)  d_in[3];
    const float* gl_w1     = (const float*)d_in[4];
    const float* gl_b1     = (const float*)d_in[5];
    const float* gl_w2     = (const float*)d_in[6];
    const float* gl_b2     = (const float*)d_in[7];
    const float* glp       = (const float*)d_in[8];
    const float* gcn_w     = (const float*)d_in[9];
    const float* vvec      = (const float*)d_in[10];
    const float* wih0      = (const float*)d_in[11];
    const float* whh0      = (const float*)d_in[12];
    const float* b0        = (const float*)d_in[13];
    const float* wih1      = (const float*)d_in[14];
    const float* whh1      = (const float*)d_in[15];
    const float* b1        = (const float*)d_in[16];
    const float* fcw       = (const float*)d_in[17];
    const float* fcb       = (const float*)d_in[18];

    uint8_t* wsb = (uint8_t*)d_ws;
    uint4*          zlin = (uint4*)(wsb);
    unsigned short* wb0  = (unsigned short*)(wsb + WB0_OFF);
    unsigned short* wb1  = (unsigned short*)(wsb + WB1_OFF);
    unsigned short* wpk  = (unsigned short*)(wsb + WPK_OFF);
    unsigned short* gpk  = (unsigned short*)(wsb + GPK_OFF);
    float* out_adj = (float*)d_out;
    float* out_y   = out_adj + ADJSZ;

    kernPrep<<<dim3(1248), dim3(256), 0, stream>>>(wih0, whh0, wih1, whh1,
                                                   gl_w1, gl_w2, gcn_w,
                                                   wb0, wb1, wpk, gpk);
    kernA<<<dim3(DB*DD), dim3(256), 0, stream>>>(x, adj_real, infection, day_order,
                                                 gl_b1, gl_b2, glp, vvec,
                                                 (const v8bf*)wpk, (const v8bf*)gpk,
                                                 out_adj, zlin);
    kernB<<<dim3(GBLK), dim3(1024), 0, stream>>>(zlin, (const v8bf*)wb0,
                                                 (const v8bf*)wb1, b0, b1, infection,
                                                 fcw, fcb, out_y);
}